// Round 9
// baseline (407.424 us; speedup 1.0000x reference)
//
#include <hip/hip_runtime.h>

#define NTOK 8192
#define DIM  512
#define MHID 2048
#define EHID 1024
#define NEXP 8
#define RBLK 64   // tokens per router block

using half_t = _Float16;
typedef _Float16 f16x8 __attribute__((ext_vector_type(8)));
typedef float    f32x16 __attribute__((ext_vector_type(16)));

#define MFMA32(a, b, c) __builtin_amdgcn_mfma_f32_32x32x16_f16((a), (b), (c), 0, 0, 0)

typedef const __attribute__((address_space(1))) void* gas_ptr;
typedef __attribute__((address_space(3))) void*       las_ptr;
__device__ __forceinline__ void gl16(const void* g, void* l) {
    __builtin_amdgcn_global_load_lds((gas_ptr)g, (las_ptr)l, 16, 0, 0);
}

__device__ __forceinline__ float gelu_exact(float v) {
    return 0.5f * v * (1.0f + erff(v * 0.70710678118654752f));
}

// all-threads-return block sum over 4 waves (256 threads)
__device__ __forceinline__ float block_sum4(float v, float* red, int tid) {
#pragma unroll
    for (int off = 32; off; off >>= 1) v += __shfl_down(v, off);
    if ((tid & 63) == 0) red[tid >> 6] = v;
    __syncthreads();
    float r = red[0] + red[1] + red[2] + red[3];
    __syncthreads();
    return r;
}

// ---------------- LN1 + fp16 hi/lo split ----------------
__global__ __launch_bounds__(256) void ln1_split_kernel(
    const float* __restrict__ x, const float* __restrict__ g, const float* __restrict__ b,
    half_t* __restrict__ xh, half_t* __restrict__ xl)
{
    const int row = blockIdx.x, tid = threadIdx.x;
    __shared__ float red[4];
    const size_t base = (size_t)row * DIM;
    float2 v = reinterpret_cast<const float2*>(x + base)[tid];
    float mean = block_sum4(v.x + v.y, red, tid) * (1.0f / DIM);
    float d0 = v.x - mean, d1 = v.y - mean;
    float var = block_sum4(d0 * d0 + d1 * d1, red, tid) * (1.0f / DIM);
    float rstd = rsqrtf(var + 1e-5f);
    int d = tid * 2;
    float y0 = d0 * rstd * g[d]     + b[d];
    float y1 = d1 * rstd * g[d + 1] + b[d + 1];
    half_t h0 = (half_t)y0, h1 = (half_t)y1;
    xh[base + d] = h0;  xh[base + d + 1] = h1;
    xl[base + d]     = (half_t)(y0 - (float)h0);
    xl[base + d + 1] = (half_t)(y1 - (float)h1);
}

// ---- x2 = x + (p0+p1+b2) ; x3 = LN2(x2) + x2 ; write x3 (f32, over p0) + f16 ----
__global__ __launch_bounds__(256) void resid_ln2_kernel(
    const float* __restrict__ x, float* __restrict__ p0, const float* __restrict__ p1,
    const float* __restrict__ b2,
    const float* __restrict__ g, const float* __restrict__ b,
    half_t* __restrict__ x3h)
{
    const int row = blockIdx.x, tid = threadIdx.x;
    __shared__ float red[4];
    const size_t base = (size_t)row * DIM;
    float2 xv = reinterpret_cast<const float2*>(x + base)[tid];
    float2 h0 = reinterpret_cast<float2*>(p0 + base)[tid];
    float2 h1 = reinterpret_cast<const float2*>(p1 + base)[tid];
    float2 bb = reinterpret_cast<const float2*>(b2)[tid];
    float z0 = xv.x + h0.x + h1.x + bb.x, z1 = xv.y + h0.y + h1.y + bb.y;
    float mean = block_sum4(z0 + z1, red, tid) * (1.0f / DIM);
    float d0 = z0 - mean, d1 = z1 - mean;
    float var = block_sum4(d0 * d0 + d1 * d1, red, tid) * (1.0f / DIM);
    float rstd = rsqrtf(var + 1e-5f);
    int d = tid * 2;
    float y0 = d0 * rstd * g[d]     + b[d]     + z0;
    float y1 = d1 * rstd * g[d + 1] + b[d + 1] + z1;
    float2 o; o.x = y0; o.y = y1;
    reinterpret_cast<float2*>(p0 + base)[tid] = o;
    x3h[base + d]     = (half_t)y0;
    x3h[base + d + 1] = (half_t)y1;
}

// ---------------- transpose [R][C] -> [C][R], cast to f16 (optional lo split) ----------------
__global__ void transpose_split_kernel(const float* __restrict__ in,
                                       half_t* __restrict__ oh, half_t* __restrict__ ol,
                                       int R, int C)
{
    __shared__ float t[32][33];
    const size_t mo = (size_t)blockIdx.z * (size_t)R * (size_t)C;
    const int c0 = blockIdx.x * 32, r0 = blockIdx.y * 32;
    const int tx = threadIdx.x, ty = threadIdx.y;
    for (int i = ty; i < 32; i += 8) t[i][tx] = in[mo + (size_t)(r0 + i) * C + c0 + tx];
    __syncthreads();
    for (int i = ty; i < 32; i += 8) {
        float v = t[tx][i];
        size_t o = mo + (size_t)(c0 + i) * R + r0 + tx;
        half_t h = (half_t)v;
        oh[o] = h;
        if (ol) ol[o] = (half_t)(v - (float)h);
    }
}

// ======== split-3 f16 MFMA GEMM: A via LDS, B DIRECT global->VGPR (L2-served) ========
// A: [M][K] f16 hi/lo.  B: [Nc][K] f16 hi/lo (pre-transposed).  BM=256, 8 waves in a
// WR x WC grid (WC = 8/WR), per-wave tile (8/WR*32) x (NREP*32), BN = WC*NREP*32.
// LDS holds ONLY A (2 buffers x 32KB, slot-XOR swizzle); B fragments are per-lane 16B
// global loads into a double-buffered register set, prefetched one K-step ahead.
// Per step: {4 gl16 A(s+1) + 4*NREP B-loads(s+1)} -> s_waitcnt vmcnt(12) (step s
// ready; s+1 rides under compute) -> barrier -> 2 phases of {A ds_read + MFMA}.
// EPI==1: gelu(acc+bias) -> split f16 hi/lo.  EPI==0: raw acc -> f32 partial
// (split-K buffer by blockIdx.z; kbeg = z*Ktile).
template <int EPI, int WR, int NREP>
__global__ __launch_bounds__(512, 2) void gemm8_kernel(
    const half_t* __restrict__ A0, const half_t* __restrict__ A1,
    const half_t* __restrict__ B0, const half_t* __restrict__ B1,
    const float* __restrict__ bias,
    float* __restrict__ Cf0, float* __restrict__ Cf1,
    half_t* __restrict__ Ch, half_t* __restrict__ Cl,
    int Nc, int K, int Ktile)
{
    constexpr int WC = 8 / WR;
    constexpr int WM = 8 / WR;                 // 32-row m-frags per wave (256/32/WR)
    constexpr int BN = WC * NREP * 32;
    __shared__ __align__(16) half_t lds[2 * 16384];   // 2 x (A0 8192 + A1 8192) halves

    const int m0 = blockIdx.x * 256, n0 = blockIdx.y * BN;
    const int kbeg = blockIdx.z * Ktile;
    float* Cf = blockIdx.z ? Cf1 : Cf0;
    const int tid = threadIdx.x;
    const int lane = tid & 63, wid = tid >> 6;
    const int wr = wid / WC, wc = wid % WC;
    const int l31 = lane & 31, l5 = lane >> 5;

    // ---- A staging: 2048 chunks of 16B per buffer; thread stages 4 (lane-linear dest,
    // slot-XOR applied on the global source).
    const half_t* gsrc[4];
    {
        const half_t* A0p = A0 + (size_t)m0 * K + kbeg;
        const half_t* A1p = A1 + (size_t)m0 * K + kbeg;
#pragma unroll
        for (int i = 0; i < 4; i++) {
            int c = tid + 512 * i;
            const half_t* base = (c < 1024) ? A0p : A1p;
            int cm = c & 1023;
            int r = cm >> 2, ss = (cm & 3) ^ ((r >> 1) & 3);
            gsrc[i] = base + (size_t)r * K + ss * 8;
        }
    }

    // ---- A fragment LDS offsets (elems within buffer, A1 at +8192)
    int oa[WM][2];
#pragma unroll
    for (int m = 0; m < WM; m++)
#pragma unroll
        for (int kh = 0; kh < 2; kh++) {
            int ra = wr * (WM * 32) + m * 32 + l31;
            oa[m][kh] = ra * 32 + (((l5 + 2 * kh) ^ ((ra >> 1) & 3)) << 3);
        }

    // ---- B fragment global pointers (per lane): row-major [Nc][K]
    const half_t* pbh[NREP];
    const half_t* pbl[NREP];
#pragma unroll
    for (int n = 0; n < NREP; n++) {
        int rb = n0 + wc * (NREP * 32) + n * 32 + l31;
        size_t o = (size_t)rb * K + kbeg + l5 * 8;
        pbh[n] = B0 + o;
        pbl[n] = B1 + o;
    }

    struct BF { f16x8 h[2][NREP]; f16x8 l[2][NREP]; };
    BF fA, fB;
    auto loadB = [&](BF& f, int kof) {
#pragma unroll
        for (int kh = 0; kh < 2; kh++)
#pragma unroll
            for (int n = 0; n < NREP; n++) {
                f.h[kh][n] = *(const f16x8*)(pbh[n] + kof + kh * 16);
                f.l[kh][n] = *(const f16x8*)(pbl[n] + kof + kh * 16);
            }
    };

    f32x16 acc[WM][NREP];
#pragma unroll
    for (int m = 0; m < WM; m++)
#pragma unroll
        for (int n = 0; n < NREP; n++)
#pragma unroll
            for (int q = 0; q < 16; q++) acc[m][n][q] = 0.f;

    auto stageA = [&](int bsel, int kof) {
#pragma unroll
        for (int i = 0; i < 4; i++)
            gl16(gsrc[i] + kof, &lds[bsel * 16384 + (tid + 512 * i) * 8]);
    };
    auto phase = [&](const half_t* buf, int kh, const BF& f) {
        __builtin_amdgcn_s_setprio(1);
#pragma unroll
        for (int m = 0; m < WM; m++) {
            f16x8 ah = *(const f16x8*)(buf + oa[m][kh]);
            f16x8 al = *(const f16x8*)(buf + 8192 + oa[m][kh]);
#pragma unroll
            for (int n = 0; n < NREP; n++) {
                acc[m][n] = MFMA32(ah, f.h[kh][n], acc[m][n]);
                acc[m][n] = MFMA32(al, f.h[kh][n], acc[m][n]);
                acc[m][n] = MFMA32(ah, f.l[kh][n], acc[m][n]);
            }
        }
        __builtin_amdgcn_s_setprio(0);
    };

    const half_t* buf0 = &lds[0];
    const half_t* buf1 = &lds[16384];
    const int nsteps = Ktile / 32;   // even (>=2) for all our shapes

    stageA(0, 0); loadB(fA, 0);
#pragma unroll 1
    for (int s = 0; s + 2 < nsteps; s += 2) {
        stageA(1, (s + 1) * 32); loadB(fB, (s + 1) * 32);
        asm volatile("s_waitcnt vmcnt(12)" ::: "memory");
        __builtin_amdgcn_s_barrier();
        phase(buf0, 0, fA);
        __builtin_amdgcn_s_barrier();
        phase(buf0, 1, fA);
        __builtin_amdgcn_s_barrier();
        stageA(0, (s + 2) * 32); loadB(fA, (s + 2) * 32);
        asm volatile("s_waitcnt vmcnt(12)" ::: "memory");
        __builtin_amdgcn_s_barrier();
        phase(buf1, 0, fB);
        __builtin_amdgcn_s_barrier();
        phase(buf1, 1, fB);
        __builtin_amdgcn_s_barrier();
    }
    stageA(1, (nsteps - 1) * 32); loadB(fB, (nsteps - 1) * 32);
    asm volatile("s_waitcnt vmcnt(12)" ::: "memory");
    __builtin_amdgcn_s_barrier();
    phase(buf0, 0, fA);
    __builtin_amdgcn_s_barrier();
    phase(buf0, 1, fA);
    asm volatile("s_waitcnt vmcnt(0)" ::: "memory");
    __builtin_amdgcn_s_barrier();
    phase(buf1, 0, fB);
    __builtin_amdgcn_s_barrier();
    phase(buf1, 1, fB);

    // C/D 32x32 layout: col = lane&31, row = 4*(lane>>5) + 8*(reg>>2) + (reg&3)
    const int er = 4 * l5;
#pragma unroll
    for (int m = 0; m < WM; m++)
#pragma unroll
        for (int n = 0; n < NREP; n++) {
            int cc = n0 + wc * (NREP * 32) + n * 32 + l31;
            float bv = (EPI == 1) ? bias[cc] : 0.f;
#pragma unroll
            for (int reg = 0; reg < 16; reg++) {
                int rr = m0 + wr * (WM * 32) + m * 32 + er + 8 * (reg >> 2) + (reg & 3);
                float v = acc[m][n][reg] + bv;
                size_t o = (size_t)rr * Nc + cc;
                if (EPI == 1) {
                    float ge = gelu_exact(v);
                    half_t h = (half_t)ge;
                    Ch[o] = h;
                    Cl[o] = (half_t)(ge - (float)h);
                } else {
                    Cf[o] = v;
                }
            }
        }
}

// ---------------- router: logits, top2, gates, block-aggregated expert lists ----------------
// cnt is PADDED: expert e's counter lives at cnt[e*32] (128 B apart -> 8 cachelines).
__global__ __launch_bounds__(256) void router_kernel(
    const float* __restrict__ x3, const float* __restrict__ wrm,
    int* __restrict__ cnt, int* __restrict__ aid, float* __restrict__ gate)
{
    __shared__ float wl[NEXP][DIM];
    __shared__ int   texp[RBLK * 2];
    __shared__ float tgate[RBLK * 2];
    __shared__ int   lslot[RBLK * 2];
    __shared__ int   lcnt[NEXP], lbase[NEXP];
    const int tid = threadIdx.x;
    for (int i = tid; i < NEXP * DIM / 4; i += 256)
        reinterpret_cast<float4*>(&wl[0][0])[i] = reinterpret_cast<const float4*>(wrm)[i];
    if (tid < NEXP) lcnt[tid] = 0;
    __syncthreads();
    const int w = tid >> 6, lane = tid & 63;
#pragma unroll 1
    for (int t = 0; t < RBLK / 4; ++t) {
        const int lt = w * (RBLK / 4) + t;
        const int token = blockIdx.x * RBLK + lt;
        const float* xr = x3 + (size_t)token * DIM;
        float a[NEXP];
#pragma unroll
        for (int e = 0; e < NEXP; e++) a[e] = 0.f;
#pragma unroll
        for (int d0 = 0; d0 < DIM; d0 += 64) {
            float xv = xr[d0 + lane];
#pragma unroll
            for (int e = 0; e < NEXP; e++) a[e] += xv * wl[e][d0 + lane];
        }
#pragma unroll
        for (int e = 0; e < NEXP; e++)
#pragma unroll
            for (int off = 32; off; off >>= 1) a[e] += __shfl_xor(a[e], off);
        if (lane == 0) {
            int i1 = 0; float v1 = a[0];
#pragma unroll
            for (int e = 1; e < NEXP; e++) if (a[e] > v1) { v1 = a[e]; i1 = e; }
            int i2 = -1; float v2 = -3.4e38f;
#pragma unroll
            for (int e = 0; e < NEXP; e++) if (e != i1 && a[e] > v2) { v2 = a[e]; i2 = e; }
            float e2 = expf(v2 - v1);
            float g1 = 1.0f / (1.0f + e2);
            texp[lt * 2]      = i1; tgate[lt * 2]      = g1;
            texp[lt * 2 + 1]  = i2; tgate[lt * 2 + 1]  = 1.0f - g1;
        }
    }
    __syncthreads();
    if (tid < RBLK * 2) lslot[tid] = atomicAdd(&lcnt[texp[tid]], 1);
    __syncthreads();
    if (tid < NEXP) lbase[tid] = atomicAdd(&cnt[tid * 32], lcnt[tid]);
    __syncthreads();
    if (tid < RBLK * 2) {
        const int e = texp[tid];
        const int asg = blockIdx.x * (RBLK * 2) + tid;   // token*2 + k
        aid[e * NTOK + lbase[e] + lslot[tid]] = asg;
        gate[asg] = tgate[tid];
    }
}

// ---------------- expert GEMM1: He[a] = gelu(x3[tok] @ ew1[e] + eb1[e]) ----------------
// A (gathered tokens) via LDS; B (expert weights) DIRECT global->VGPR.
__global__ __launch_bounds__(256) void egemm1_kernel(
    const half_t* __restrict__ X,   // [NTOK][DIM]
    const half_t* __restrict__ W,   // [E][EHID][DIM]
    const float* __restrict__ eb1,
    const int* __restrict__ cnt, const int* __restrict__ aid,
    half_t* __restrict__ He)        // [2*NTOK][EHID]
{
    const int bid = blockIdx.x;
    const int e = bid >> 9, rem = bid & 511;
    const int mt = rem >> 3, nt = rem & 7;
    const int ne = cnt[e * 32];
    if (mt * 128 >= ne) return;
    __shared__ __align__(16) half_t As[2][128 * 32];
    __shared__ int rowmap[128];
    const int tid = threadIdx.x;
    if (tid < 128) {
        int slot = mt * 128 + tid;
        rowmap[tid] = (slot < ne) ? aid[e * NTOK + slot] : -1;
    }
    __syncthreads();
    const int lane = tid & 63, wid = tid >> 6;
    const int wr = wid >> 1, wc = wid & 1;
    const int l31 = lane & 31, l5 = lane >> 5;
    const int c0 = tid, c1 = tid + 256;
    const int r0 = c0 >> 2, s0 = (c0 & 3) ^ ((r0 >> 1) & 3);
    const int r1 = c1 >> 2, s1 = (c1 & 3) ^ ((r1 >> 1) & 3);
    const int a0r = rowmap[r0], a1r = rowmap[r1];
    const half_t* pa0 = X + (size_t)(a0r >= 0 ? (a0r >> 1) : 0) * DIM + s0 * 8;
    const half_t* pa1 = X + (size_t)(a1r >= 0 ? (a1r >> 1) : 0) * DIM + s1 * 8;
    const half_t* Wb = W + (size_t)e * EHID * DIM;
    const half_t* pb0 = Wb + (size_t)(nt * 128 + wc * 64 + l31) * DIM + l5 * 8;
    const half_t* pb1 = Wb + (size_t)(nt * 128 + wc * 64 + 32 + l31) * DIM + l5 * 8;

    int oa[2][2];
#pragma unroll
    for (int i = 0; i < 2; i++)
#pragma unroll
        for (int kh = 0; kh < 2; kh++) {
            int ra = wr * 64 + i * 32 + l31;
            oa[i][kh] = ra * 32 + (((l5 + kh * 2) ^ ((ra >> 1) & 3)) << 3);
        }
    f32x16 acc[2][2];
#pragma unroll
    for (int i = 0; i < 2; i++)
#pragma unroll
        for (int j = 0; j < 2; j++)
#pragma unroll
            for (int q = 0; q < 16; q++) acc[i][j][q] = 0.f;

    auto stage = [&](int bsel, int k0) {
        gl16(pa0 + k0, &As[bsel][c0 * 8]);
        gl16(pa1 + k0, &As[bsel][c1 * 8]);
    };
    auto compute = [&](int bsel, int kg) {
#pragma unroll
        for (int kh = 0; kh < 2; kh++) {
            f16x8 b0 = *(const f16x8*)(pb0 + kg + kh * 16);
            f16x8 b1 = *(const f16x8*)(pb1 + kg + kh * 16);
            f16x8 a0 = *(const f16x8*)(&As[bsel][0] + oa[0][kh]);
            f16x8 a1 = *(const f16x8*)(&As[bsel][0] + oa[1][kh]);
            acc[0][0] = MFMA32(a0, b0, acc[0][0]);
            acc[0][1] = MFMA32(a0, b1, acc[0][1]);
            acc[1][0] = MFMA32(a1, b0, acc[1][0]);
            acc[1][1] = MFMA32(a1, b1, acc[1][1]);
        }
    };

    stage(0, 0);
#pragma unroll 1
    for (int k0 = 0; k0 < DIM; k0 += 64) {
        __syncthreads();
        if (k0 + 32 < DIM) stage(1, k0 + 32);
        compute(0, k0);
        __syncthreads();
        if (k0 + 64 < DIM) stage(0, k0 + 64);
        compute(1, k0 + 32);
    }
    const int er = 4 * l5;
#pragma unroll
    for (int i = 0; i < 2; i++)
#pragma unroll
        for (int reg = 0; reg < 16; reg++) {
            int rloc = wr * 64 + i * 32 + er + 8 * (reg >> 2) + (reg & 3);
            int a = rowmap[rloc];
            if (a >= 0) {
#pragma unroll
                for (int j = 0; j < 2; j++) {
                    int cc = nt * 128 + wc * 64 + j * 32 + l31;
                    float v = acc[i][j][reg] + eb1[e * EHID + cc];
                    He[(size_t)a * EHID + cc] = (half_t)gelu_exact(v);
                }
            }
        }
}

// ---------------- expert GEMM2: Ye[a] = (He[a] @ ew2[e] + eb2[e]) * gate[a] ----------------
__global__ __launch_bounds__(256) void egemm2_kernel(
    const half_t* __restrict__ Hin,  // [2*NTOK][EHID]
    const half_t* __restrict__ W,    // [E][DIM][EHID]
    const float* __restrict__ eb2,
    const int* __restrict__ cnt, const int* __restrict__ aid,
    const float* __restrict__ gate,
    float* __restrict__ Ye)          // [2*NTOK][DIM]
{
    const int bid = blockIdx.x;
    const int e = bid >> 8, rem = bid & 255;
    const int mt = rem >> 2, nt = rem & 3;
    const int ne = cnt[e * 32];
    if (mt * 128 >= ne) return;
    __shared__ __align__(16) half_t As[2][128 * 32];
    __shared__ int rowmap[128];
    const int tid = threadIdx.x;
    if (tid < 128) {
        int slot = mt * 128 + tid;
        rowmap[tid] = (slot < ne) ? aid[e * NTOK + slot] : -1;
    }
    __syncthreads();
    const int lane = tid & 63, wid = tid >> 6;
    const int wr = wid >> 1, wc = wid & 1;
    const int l31 = lane & 31, l5 = lane >> 5;
    const int c0 = tid, c1 = tid + 256;
    const int r0 = c0 >> 2, s0 = (c0 & 3) ^ ((r0 >> 1) & 3);
    const int r1 = c1 >> 2, s1 = (c1 & 3) ^ ((r1 >> 1) & 3);
    const int a0r = rowmap[r0], a1r = rowmap[r1];
    const half_t* pa0 = Hin + (size_t)(a0r >= 0 ? a0r : 0) * EHID + s0 * 8;
    const half_t* pa1 = Hin + (size_t)(a1r >= 0 ? a1r : 0) * EHID + s1 * 8;
    const half_t* Wb = W + (size_t)e * DIM * EHID;
    const half_t* pb0 = Wb + (size_t)(nt * 128 + wc * 64 + l31) * EHID + l5 * 8;
    const half_t* pb1 = Wb + (size_t)(nt * 128 + wc * 64 + 32 + l31) * EHID + l5 * 8;

    int oa[2][2];
#pragma unroll
    for (int i = 0; i < 2; i++)
#pragma unroll
        for (int kh = 0; kh < 2; kh++) {
            int ra = wr * 64 + i * 32 + l31;
            oa[i][kh] = ra * 32 + (((l5 + kh * 2) ^ ((ra >> 1) & 3)) << 3);
        }
    f32x16 acc[2][2];
#pragma unroll
    for (int i = 0; i < 2; i++)
#pragma unroll
        for (int j = 0; j < 2; j++)
#pragma unroll
            for (int q = 0; q < 16; q++) acc[i][j][q] = 0.f;

    auto stage = [&](int bsel, int k0) {
        gl16(pa0 + k0, &As[bsel][c0 * 8]);
        gl16(pa1 + k0, &As[bsel][c1 * 8]);
    };
    auto compute = [&](int bsel, int kg) {
#pragma unroll
        for (int kh = 0; kh < 2; kh++) {
            f16x8 b0 = *(const f16x8*)(pb0 + kg + kh * 16);
            f16x8 b1 = *(const f16x8*)(pb1 + kg + kh * 16);
            f16x8 a0 = *(const f16x8*)(&As[bsel][0] + oa[0][kh]);
            f16x8 a1 = *(const f16x8*)(&As[bsel][0] + oa[1][kh]);
            acc[0][0] = MFMA32(a0, b0, acc[0][0]);
            acc[0][1] = MFMA32(a0, b1, acc[0][1]);
            acc[1][0] = MFMA32(a1, b0, acc[1][0]);
            acc[1][1] = MFMA32(a1, b1, acc[1][1]);
        }
    };

    stage(0, 0);
#pragma unroll 1
    for (int k0 = 0; k0 < EHID; k0 += 64) {
        __syncthreads();
        if (k0 + 32 < EHID) stage(1, k0 + 32);
        compute(0, k0);
        __syncthreads();
        if (k0 + 64 < EHID) stage(0, k0 + 64);
        compute(1, k0 + 32);
    }
    const int er = 4 * l5;
#pragma unroll
    for (int i = 0; i < 2; i++)
#pragma unroll
        for (int reg = 0; reg < 16; reg++) {
            int rloc = wr * 64 + i * 32 + er + 8 * (reg >> 2) + (reg & 3);
            int a = rowmap[rloc];
            if (a >= 0) {
                float gv = gate[a];
#pragma unroll
                for (int j = 0; j < 2; j++) {
                    int cc = nt * 128 + wc * 64 + j * 32 + l31;
                    float v = (acc[i][j][reg] + eb2[e * DIM + cc]) * gv;
                    Ye[(size_t)a * DIM + cc] = v;
                }
            }
        }
}

// ---------------- combine two expert outputs per token + final LN ----------------
__global__ __launch_bounds__(256) void combine_lnf_kernel(
    const float* __restrict__ Ye, const float* __restrict__ g, const float* __restrict__ b,
    float* __restrict__ out)
{
    const int t = blockIdx.x, tid = threadIdx.x;
    __shared__ float red[4];
    float2 y0 = reinterpret_cast<const float2*>(Ye + (size_t)(2 * t) * DIM)[tid];
    float2 y1 = reinterpret_cast<const float2*>(Ye + (size_t)(2 * t + 1) * DIM)[tid];
    float z0 = y0.x + y1.x, z1 = y0.y + y1.y;
    float mean = block_sum4(z0 + z1, red, tid) * (1.0f / DIM);
    float d0 = z0 - mean, d1 = z1 - mean;
    float var = block_sum4(d0 * d0 + d1 * d1, red, tid) * (1.0f / DIM);
    float rstd = rsqrtf(var + 1e-5f);
    int d = tid * 2;
    out[(size_t)t * DIM + d]     = d0 * rstd * g[d]     + b[d];
    out[(size_t)t * DIM + d + 1] = d1 * rstd * g[d + 1] + b[d + 1];
    if (t == 0 && tid == 0) out[(size_t)NTOK * DIM] = 0.f;  // aux_loss
}

__global__ void zero_cnt_kernel(int* cnt) {
    cnt[threadIdx.x] = 0;   // zero all 256 padded slots (8 experts * stride 32)
}

extern "C" void kernel_launch(void* const* d_in, const int* in_sizes, int n_in,
                              void* d_out, int out_size, void* d_ws, size_t ws_size,
                              hipStream_t stream)
{
    (void)in_sizes; (void)n_in; (void)out_size; (void)ws_size;
    const float* x    = (const float*)d_in[0];
    const float* ln1g = (const float*)d_in[1];
    const float* ln1b = (const float*)d_in[2];
    const float* w1   = (const float*)d_in[3];
    const float* b1   = (const float*)d_in[4];
    const float* w2   = (const float*)d_in[5];
    const float* b2   = (const float*)d_in[6];
    const float* ln2g = (const float*)d_in[7];
    const float* ln2b = (const float*)d_in[8];
    const float* wrm  = (const float*)d_in[9];
    const float* ew1  = (const float*)d_in[10];
    const float* eb1  = (const float*)d_in[11];
    const float* ew2  = (const float*)d_in[12];
    const float* eb2  = (const float*)d_in[13];
    const float* lnfg = (const float*)d_in[14];
    const float* lnfb = (const float*)d_in[15];
    float* out = (float*)d_out;

    char* w = (char*)d_ws;
    size_t off = 0;
    auto take = [&](size_t bytes) {
        char* p = w + off;
        off += bytes;
        off = (off + 255) & ~(size_t)255;
        return p;
    };
    half_t* xh_h  = (half_t*)take((size_t)NTOK * DIM * 2);   // also split-K partial p1 (f32, 16MB)
    half_t* xh_l  = (half_t*)take((size_t)NTOK * DIM * 2);
    half_t* w1t_h = (half_t*)take((size_t)DIM * MHID * 2);
    half_t* w1t_l = (half_t*)take((size_t)DIM * MHID * 2);
    half_t* w2t_h = (half_t*)take((size_t)MHID * DIM * 2);
    half_t* w2t_l = (half_t*)take((size_t)MHID * DIM * 2);
    char*   big   = take((size_t)NTOK * MHID * 2 * 2);        // 64 MiB: a1 hi/lo, later He + Ye
    half_t* a1h   = (half_t*)big;
    half_t* a1l   = (half_t*)(big + (size_t)NTOK * MHID * 2);
    half_t* heh   = (half_t*)big;                              // alias (a1 dead after gemm8<0>)
    float*  yef   = (float*)(big + (size_t)NTOK * MHID * 2);   // alias
    float*  x3f   = (float*)take((size_t)NTOK * DIM * 4);      // split-K partial p0, then x3 f32
    half_t* x3h   = (half_t*)take((size_t)NTOK * DIM * 2);
    half_t* ew1t  = (half_t*)take((size_t)NEXP * DIM * EHID * 2);
    half_t* ew2t  = (half_t*)take((size_t)NEXP * EHID * DIM * 2);
    int*    cnt   = (int*)take(1024);                          // 8 experts, 128 B apart
    int*    aid   = (int*)take((size_t)NEXP * NTOK * 4);
    float*  gate  = (float*)take((size_t)NTOK * 2 * 4);

    float* p0 = x3f;
    float* p1 = (float*)xh_h;   // xh_h+xh_l = contiguous 16 MB, dead after gemm8<1>

    zero_cnt_kernel<<<1, 256, 0, stream>>>(cnt);
    ln1_split_kernel<<<NTOK, 256, 0, stream>>>(x, ln1g, ln1b, xh_h, xh_l);
    transpose_split_kernel<<<dim3(MHID / 32, DIM / 32, 1), dim3(32, 8), 0, stream>>>(w1, w1t_h, w1t_l, DIM, MHID);
    transpose_split_kernel<<<dim3(DIM / 32, MHID / 32, 1), dim3(32, 8), 0, stream>>>(w2, w2t_h, w2t_l, MHID, DIM);
    transpose_split_kernel<<<dim3(EHID / 32, DIM / 32, NEXP), dim3(32, 8), 0, stream>>>(ew1, ew1t, (half_t*)0, DIM, EHID);
    transpose_split_kernel<<<dim3(DIM / 32, EHID / 32, NEXP), dim3(32, 8), 0, stream>>>(ew2, ew2t, (half_t*)0, EHID, DIM);
    // MLP GEMM1: [8192x512] @ [512x2048].  256x256 tile, waves 2x4, B-direct.
    gemm8_kernel<1, 2, 2><<<dim3(NTOK / 256, MHID / 256, 1), 512, 0, stream>>>(
        xh_h, xh_l, w1t_h, w1t_l, b1, (float*)0, (float*)0, a1h, a1l, MHID, DIM, DIM);
    // MLP GEMM2: [8192x2048] @ [2048x512].  256x128 tile, waves 4x2, split-K=2, B-direct.
    gemm8_kernel<0, 4, 2><<<dim3(NTOK / 256, DIM / 128, 2), 512, 0, stream>>>(
        a1h, a1l, w2t_h, w2t_l, (const float*)0, p0, p1, (half_t*)0, (half_t*)0, DIM, MHID, MHID / 2);
    resid_ln2_kernel<<<NTOK, 256, 0, stream>>>(x, p0, p1, b2, ln2g, ln2b, x3h);
    router_kernel<<<NTOK / RBLK, 256, 0, stream>>>(x3f, wrm, cnt, aid, gate);
    egemm1_kernel<<<NEXP * (NTOK / 128) * (EHID / 128), 256, 0, stream>>>(x3h, ew1t, eb1, cnt, aid, heh);
    egemm2_kernel<<<NEXP * (NTOK / 128) * (DIM / 128), 256, 0, stream>>>(heh, ew2t, eb2, cnt, aid, gate, yef);
    combine_lnf_kernel<<<NTOK, 256, 0, stream>>>(yef, lnfg, lnfb, out);
}

// Round 10
// 309.070 us; speedup vs baseline: 1.3182x; 1.3182x over previous
//
#include <hip/hip_runtime.h>

#define NTOK 8192
#define DIM  512
#define MHID 2048
#define EHID 1024
#define NEXP 8
#define RBLK 64   // tokens per router block

using half_t = _Float16;
typedef _Float16 f16x8 __attribute__((ext_vector_type(8)));
typedef float    f32x16 __attribute__((ext_vector_type(16)));

#define MFMA32(a, b, c) __builtin_amdgcn_mfma_f32_32x32x16_f16((a), (b), (c), 0, 0, 0)

typedef const __attribute__((address_space(1))) void* gas_ptr;
typedef __attribute__((address_space(3))) void*       las_ptr;
__device__ __forceinline__ void gl16(const void* g, void* l) {
    __builtin_amdgcn_global_load_lds((gas_ptr)g, (las_ptr)l, 16, 0, 0);
}

__device__ __forceinline__ float gelu_exact(float v) {
    return 0.5f * v * (1.0f + erff(v * 0.70710678118654752f));
}

// all-threads-return block sum over 4 waves (256 threads)
__device__ __forceinline__ float block_sum4(float v, float* red, int tid) {
#pragma unroll
    for (int off = 32; off; off >>= 1) v += __shfl_down(v, off);
    if ((tid & 63) == 0) red[tid >> 6] = v;
    __syncthreads();
    float r = red[0] + red[1] + red[2] + red[3];
    __syncthreads();
    return r;
}

// ---------------- LN1 + fp16 hi/lo split (+ folds cnt zeroing, saves a launch) ----------------
__global__ __launch_bounds__(256) void ln1_split_kernel(
    const float* __restrict__ x, const float* __restrict__ g, const float* __restrict__ b,
    half_t* __restrict__ xh, half_t* __restrict__ xl, int* __restrict__ cnt)
{
    const int row = blockIdx.x, tid = threadIdx.x;
    if (row == 0) cnt[tid] = 0;   // zero all 256 padded slots (8 experts * stride 32)
    __shared__ float red[4];
    const size_t base = (size_t)row * DIM;
    float2 v = reinterpret_cast<const float2*>(x + base)[tid];
    float mean = block_sum4(v.x + v.y, red, tid) * (1.0f / DIM);
    float d0 = v.x - mean, d1 = v.y - mean;
    float var = block_sum4(d0 * d0 + d1 * d1, red, tid) * (1.0f / DIM);
    float rstd = rsqrtf(var + 1e-5f);
    int d = tid * 2;
    float y0 = d0 * rstd * g[d]     + b[d];
    float y1 = d1 * rstd * g[d + 1] + b[d + 1];
    half_t h0 = (half_t)y0, h1 = (half_t)y1;
    xh[base + d] = h0;  xh[base + d + 1] = h1;
    xl[base + d]     = (half_t)(y0 - (float)h0);
    xl[base + d + 1] = (half_t)(y1 - (float)h1);
}

// ---- x2 = x + (p0+p1+b2) ; x3 = LN2(x2) + x2 ; write x3 (f32, over p0) + f16 ----
__global__ __launch_bounds__(256) void resid_ln2_kernel(
    const float* __restrict__ x, float* __restrict__ p0, const float* __restrict__ p1,
    const float* __restrict__ b2,
    const float* __restrict__ g, const float* __restrict__ b,
    half_t* __restrict__ x3h)
{
    const int row = blockIdx.x, tid = threadIdx.x;
    __shared__ float red[4];
    const size_t base = (size_t)row * DIM;
    float2 xv = reinterpret_cast<const float2*>(x + base)[tid];
    float2 h0 = reinterpret_cast<float2*>(p0 + base)[tid];
    float2 h1 = reinterpret_cast<const float2*>(p1 + base)[tid];
    float2 bb = reinterpret_cast<const float2*>(b2)[tid];
    float z0 = xv.x + h0.x + h1.x + bb.x, z1 = xv.y + h0.y + h1.y + bb.y;
    float mean = block_sum4(z0 + z1, red, tid) * (1.0f / DIM);
    float d0 = z0 - mean, d1 = z1 - mean;
    float var = block_sum4(d0 * d0 + d1 * d1, red, tid) * (1.0f / DIM);
    float rstd = rsqrtf(var + 1e-5f);
    int d = tid * 2;
    float y0 = d0 * rstd * g[d]     + b[d]     + z0;
    float y1 = d1 * rstd * g[d + 1] + b[d + 1] + z1;
    float2 o; o.x = y0; o.y = y1;
    reinterpret_cast<float2*>(p0 + base)[tid] = o;
    x3h[base + d]     = (half_t)y0;
    x3h[base + d + 1] = (half_t)y1;
}

// ---- ALL weight transposes in ONE launch: [R][C] -> [C][R], f16 (optional lo split) ----
__global__ void transpose_all_kernel(
    const float* __restrict__ w1, const float* __restrict__ w2,
    const float* __restrict__ ew1, const float* __restrict__ ew2,
    half_t* __restrict__ w1t_h, half_t* __restrict__ w1t_l,
    half_t* __restrict__ w2t_h, half_t* __restrict__ w2t_l,
    half_t* __restrict__ ew1t, half_t* __restrict__ ew2t)
{
    int bb = blockIdx.x;
    const float* in; half_t* oh; half_t* ol = (half_t*)0;
    int R, C, cx, cy; size_t mo = 0;
    if (bb < 1024)      { in = w1;  oh = w1t_h; ol = w1t_l; R = 512;  C = 2048; cx = bb & 63; cy = bb >> 6; }
    else if (bb < 2048) { bb -= 1024; in = w2;  oh = w2t_h; ol = w2t_l; R = 2048; C = 512; cx = bb & 15; cy = bb >> 4; }
    else if (bb < 6144) { bb -= 2048; int e = bb >> 9, r = bb & 511;
                          in = ew1; oh = ew1t; R = 512;  C = 1024; mo = (size_t)e * R * C; cx = r & 31; cy = r >> 5; }
    else                { bb -= 6144; int e = bb >> 9, r = bb & 511;
                          in = ew2; oh = ew2t; R = 1024; C = 512;  mo = (size_t)e * R * C; cx = r & 15; cy = r >> 4; }
    __shared__ float t[32][33];
    const int c0 = cx * 32, r0 = cy * 32;
    const int tx = threadIdx.x, ty = threadIdx.y;
    for (int i = ty; i < 32; i += 8) t[i][tx] = in[mo + (size_t)(r0 + i) * C + c0 + tx];
    __syncthreads();
    for (int i = ty; i < 32; i += 8) {
        float v = t[tx][i];
        size_t o = mo + (size_t)(c0 + i) * R + r0 + tx;
        half_t h = (half_t)v;
        oh[o] = h;
        if (ol) ol[o] = (half_t)(v - (float)h);
    }
}

// ======== split-3 f16 MFMA GEMM, 256-row tile, 8 waves, counted-vmcnt, 2 barriers/step ========
// A: [M][K] f16 hi/lo.  B: [Nc][K] f16 hi/lo (pre-transposed).  BM=256, BN=NREP*128,
// BK=32, waves 2(M)x4(N), per-wave out 128 x NREP*32.  LDS per buffer [A0|A1|B0|B1]
// chunk-linear (gl16 dest lane-linear, m104); slot-XOR swizzle on global source +
// fragment-read side.  Per step s: issue tile s+1's loads -> s_waitcnt vmcnt(LOADS)
// (tile s done; s+1 rides under the 48-MFMA burst) -> barrier -> reads+MFMA (both kh,
// no mid barrier: buffer is stable) -> barrier (WAR).  Tail peeled with vmcnt(0).
// EPI==1: gelu(acc+bias) -> split f16 hi/lo.  EPI==0: raw acc -> f32 partial
// (split-K buffer by blockIdx.z; kbeg = z*Ktile).
template <int EPI, int NREP>
__global__ __launch_bounds__(512, 2) void gemm8_kernel(
    const half_t* __restrict__ A0, const half_t* __restrict__ A1,
    const half_t* __restrict__ B0, const half_t* __restrict__ B1,
    const float* __restrict__ bias,
    float* __restrict__ Cf0, float* __restrict__ Cf1,
    half_t* __restrict__ Ch, half_t* __restrict__ Cl,
    int Nc, int K, int Ktile)
{
    constexpr int BN    = NREP * 128;
    constexpr int LOADS = 4 + 2 * NREP;            // 16B chunks staged per thread per K-step
    constexpr int TOT   = 16384 + NREP * 8192;     // half_t elems per LDS buffer
    __shared__ __align__(16) half_t lds[2 * TOT];

    const int m0 = blockIdx.x * 256, n0 = blockIdx.y * BN;
    const int kbeg = blockIdx.z * Ktile;
    float* Cf = blockIdx.z ? Cf1 : Cf0;
    const int tid = threadIdx.x;
    const int lane = tid & 63, wid = tid >> 6;
    const int wr = wid >> 2, wc = wid & 3;         // 2 x 4 wave grid
    const int l31 = lane & 31, l5 = lane >> 5;

    // ---- staging descriptors: chunk c = tid + 512*i; [A0|A1|B0|B1] boundaries are
    // 512-aligned so a wave never straddles a matrix. LDS dest = c*16B (lane-linear).
    const half_t* gsrc[LOADS];
    {
        const half_t* A0p = A0 + (size_t)m0 * K + kbeg;
        const half_t* A1p = A1 + (size_t)m0 * K + kbeg;
        const half_t* B0p = B0 + (size_t)n0 * K + kbeg;
        const half_t* B1p = B1 + (size_t)n0 * K + kbeg;
#pragma unroll
        for (int i = 0; i < LOADS; i++) {
            int c = tid + 512 * i;
            const half_t* base; int cm;
            if (c < 1024)                  { base = A0p; cm = c; }
            else if (c < 2048)             { base = A1p; cm = c - 1024; }
            else if (c < 2048 + NREP * 512){ base = B0p; cm = c - 2048; }
            else                           { base = B1p; cm = c - 2048 - NREP * 512; }
            int r = cm >> 2, ss = (cm & 3) ^ ((r >> 1) & 3);
            gsrc[i] = base + (size_t)r * K + ss * 8;
        }
    }

    // ---- fragment LDS offsets (elems within buffer): row stride 32, slot-XOR read
    int oa[4][2], ob[NREP][2];
#pragma unroll
    for (int m = 0; m < 4; m++)
#pragma unroll
        for (int kh = 0; kh < 2; kh++) {
            int ra = wr * 128 + m * 32 + l31;
            oa[m][kh] = ra * 32 + (((l5 + 2 * kh) ^ ((ra >> 1) & 3)) << 3);
        }
#pragma unroll
    for (int n = 0; n < NREP; n++)
#pragma unroll
        for (int kh = 0; kh < 2; kh++) {
            int rb = wc * (NREP * 32) + n * 32 + l31;
            ob[n][kh] = rb * 32 + (((l5 + 2 * kh) ^ ((rb >> 1) & 3)) << 3);
        }

    f32x16 acc[4][NREP];
#pragma unroll
    for (int m = 0; m < 4; m++)
#pragma unroll
        for (int n = 0; n < NREP; n++)
#pragma unroll
            for (int q = 0; q < 16; q++) acc[m][n][q] = 0.f;

    auto stage = [&](int bsel, int kof) {
#pragma unroll
        for (int i = 0; i < LOADS; i++)
            gl16(gsrc[i] + kof, &lds[bsel * TOT + (tid + 512 * i) * 8]);
    };
    auto compute = [&](int p) {
        const half_t* buf = &lds[p ? TOT : 0];
        __builtin_amdgcn_s_setprio(1);
#pragma unroll
        for (int kh = 0; kh < 2; kh++) {
            f16x8 ah[4], al[4], bh[NREP], bl[NREP];
#pragma unroll
            for (int m = 0; m < 4; m++) {
                ah[m] = *(const f16x8*)(buf + oa[m][kh]);
                al[m] = *(const f16x8*)(buf + 8192 + oa[m][kh]);
            }
#pragma unroll
            for (int n = 0; n < NREP; n++) {
                bh[n] = *(const f16x8*)(buf + 16384 + ob[n][kh]);
                bl[n] = *(const f16x8*)(buf + 16384 + BN * 32 + ob[n][kh]);
            }
#pragma unroll
            for (int m = 0; m < 4; m++)
#pragma unroll
                for (int n = 0; n < NREP; n++) {
                    acc[m][n] = MFMA32(ah[m], bh[n], acc[m][n]);
                    acc[m][n] = MFMA32(al[m], bh[n], acc[m][n]);
                    acc[m][n] = MFMA32(ah[m], bl[n], acc[m][n]);
                }
        }
        __builtin_amdgcn_s_setprio(0);
    };

    const int nsteps = Ktile / 32;
    stage(0, 0);                                    // tile 0 in flight
#pragma unroll 1
    for (int s = 0; s < nsteps - 1; ++s) {
        stage((s + 1) & 1, (s + 1) * 32);           // tile s+1 in flight (buf last read at s-1)
        if constexpr (NREP == 2) asm volatile("s_waitcnt vmcnt(8)" ::: "memory");
        else                     asm volatile("s_waitcnt vmcnt(6)" ::: "memory");
        __builtin_amdgcn_s_barrier();               // tile s visible to all waves
        compute(s & 1);
        __builtin_amdgcn_s_barrier();               // WAR: all reads of buf done
    }
    asm volatile("s_waitcnt vmcnt(0)" ::: "memory");
    __builtin_amdgcn_s_barrier();
    compute((nsteps - 1) & 1);

    // C/D 32x32 layout: col = lane&31, row = 4*(lane>>5) + 8*(reg>>2) + (reg&3)
    const int er = 4 * l5;
#pragma unroll
    for (int m = 0; m < 4; m++)
#pragma unroll
        for (int n = 0; n < NREP; n++) {
            int cc = n0 + wc * (NREP * 32) + n * 32 + l31;
            float bv = (EPI == 1) ? bias[cc] : 0.f;
#pragma unroll
            for (int reg = 0; reg < 16; reg++) {
                int rr = m0 + wr * 128 + m * 32 + er + 8 * (reg >> 2) + (reg & 3);
                float v = acc[m][n][reg] + bv;
                size_t o = (size_t)rr * Nc + cc;
                if (EPI == 1) {
                    float ge = gelu_exact(v);
                    half_t h = (half_t)ge;
                    Ch[o] = h;
                    Cl[o] = (half_t)(ge - (float)h);
                } else {
                    Cf[o] = v;
                }
            }
        }
}

// ---------------- router: logits, top2, gates, block-aggregated expert lists ----------------
// cnt is PADDED: expert e's counter lives at cnt[e*32] (128 B apart -> 8 cachelines).
__global__ __launch_bounds__(256) void router_kernel(
    const float* __restrict__ x3, const float* __restrict__ wrm,
    int* __restrict__ cnt, int* __restrict__ aid, float* __restrict__ gate)
{
    __shared__ float wl[NEXP][DIM];
    __shared__ int   texp[RBLK * 2];
    __shared__ float tgate[RBLK * 2];
    __shared__ int   lslot[RBLK * 2];
    __shared__ int   lcnt[NEXP], lbase[NEXP];
    const int tid = threadIdx.x;
    for (int i = tid; i < NEXP * DIM / 4; i += 256)
        reinterpret_cast<float4*>(&wl[0][0])[i] = reinterpret_cast<const float4*>(wrm)[i];
    if (tid < NEXP) lcnt[tid] = 0;
    __syncthreads();
    const int w = tid >> 6, lane = tid & 63;
#pragma unroll 1
    for (int t = 0; t < RBLK / 4; ++t) {
        const int lt = w * (RBLK / 4) + t;
        const int token = blockIdx.x * RBLK + lt;
        const float* xr = x3 + (size_t)token * DIM;
        float a[NEXP];
#pragma unroll
        for (int e = 0; e < NEXP; e++) a[e] = 0.f;
#pragma unroll
        for (int d0 = 0; d0 < DIM; d0 += 64) {
            float xv = xr[d0 + lane];
#pragma unroll
            for (int e = 0; e < NEXP; e++) a[e] += xv * wl[e][d0 + lane];
        }
#pragma unroll
        for (int e = 0; e < NEXP; e++)
#pragma unroll
            for (int off = 32; off; off >>= 1) a[e] += __shfl_xor(a[e], off);
        if (lane == 0) {
            int i1 = 0; float v1 = a[0];
#pragma unroll
            for (int e = 1; e < NEXP; e++) if (a[e] > v1) { v1 = a[e]; i1 = e; }
            int i2 = -1; float v2 = -3.4e38f;
#pragma unroll
            for (int e = 0; e < NEXP; e++) if (e != i1 && a[e] > v2) { v2 = a[e]; i2 = e; }
            float e2 = expf(v2 - v1);
            float g1 = 1.0f / (1.0f + e2);
            texp[lt * 2]      = i1; tgate[lt * 2]      = g1;
            texp[lt * 2 + 1]  = i2; tgate[lt * 2 + 1]  = 1.0f - g1;
        }
    }
    __syncthreads();
    if (tid < RBLK * 2) lslot[tid] = atomicAdd(&lcnt[texp[tid]], 1);
    __syncthreads();
    if (tid < NEXP) lbase[tid] = atomicAdd(&cnt[tid * 32], lcnt[tid]);
    __syncthreads();
    if (tid < RBLK * 2) {
        const int e = texp[tid];
        const int asg = blockIdx.x * (RBLK * 2) + tid;   // token*2 + k
        aid[e * NTOK + lbase[e] + lslot[tid]] = asg;
        gate[asg] = tgate[tid];
    }
}

// ---------------- expert GEMM1: He[a] = gelu(x3[tok] @ ew1[e] + eb1[e]) ----------------
__global__ __launch_bounds__(256) void egemm1_kernel(
    const half_t* __restrict__ X,   // [NTOK][DIM]
    const half_t* __restrict__ W,   // [E][EHID][DIM]
    const float* __restrict__ eb1,
    const int* __restrict__ cnt, const int* __restrict__ aid,
    half_t* __restrict__ He)        // [2*NTOK][EHID]
{
    const int bid = blockIdx.x;
    const int e = bid >> 9, rem = bid & 511;
    const int mt = rem >> 3, nt = rem & 7;
    const int ne = cnt[e * 32];
    if (mt * 128 >= ne) return;
    __shared__ __align__(16) half_t As[2][128 * 32];
    __shared__ __align__(16) half_t Bs[2][128 * 32];
    __shared__ int rowmap[128];
    const int tid = threadIdx.x;
    if (tid < 128) {
        int slot = mt * 128 + tid;
        rowmap[tid] = (slot < ne) ? aid[e * NTOK + slot] : -1;
    }
    __syncthreads();
    const int lane = tid & 63, wid = tid >> 6;
    const int wr = wid >> 1, wc = wid & 1;
    const int c0 = tid, c1 = tid + 256;
    const int r0 = c0 >> 2, s0 = (c0 & 3) ^ ((r0 >> 1) & 3);
    const int r1 = c1 >> 2, s1 = (c1 & 3) ^ ((r1 >> 1) & 3);
    const int a0r = rowmap[r0], a1r = rowmap[r1];
    const half_t* pa0 = X + (size_t)(a0r >= 0 ? (a0r >> 1) : 0) * DIM + s0 * 8;
    const half_t* pa1 = X + (size_t)(a1r >= 0 ? (a1r >> 1) : 0) * DIM + s1 * 8;
    const half_t* pb0 = W + (size_t)e * EHID * DIM + (size_t)(nt * 128 + r0) * DIM + s0 * 8;
    const half_t* pb1 = W + (size_t)e * EHID * DIM + (size_t)(nt * 128 + r1) * DIM + s1 * 8;

    const int l31 = lane & 31, l5 = lane >> 5;
    int oa[2][2], ob[2][2];
#pragma unroll
    for (int i = 0; i < 2; i++)
#pragma unroll
        for (int kh = 0; kh < 2; kh++) {
            int ra = wr * 64 + i * 32 + l31;
            oa[i][kh] = ra * 32 + (((l5 + kh * 2) ^ ((ra >> 1) & 3)) << 3);
            int rb = wc * 64 + i * 32 + l31;
            ob[i][kh] = rb * 32 + (((l5 + kh * 2) ^ ((rb >> 1) & 3)) << 3);
        }
    f32x16 acc[2][2];
#pragma unroll
    for (int i = 0; i < 2; i++)
#pragma unroll
        for (int j = 0; j < 2; j++)
#pragma unroll
            for (int q = 0; q < 16; q++) acc[i][j][q] = 0.f;

    auto stage = [&](int bsel, int k0) {
        gl16(pa0 + k0, &As[bsel][c0 * 8]);
        gl16(pa1 + k0, &As[bsel][c1 * 8]);
        gl16(pb0 + k0, &Bs[bsel][c0 * 8]);
        gl16(pb1 + k0, &Bs[bsel][c1 * 8]);
    };
    auto compute = [&](int bsel) {
#pragma unroll
        for (int kh = 0; kh < 2; kh++) {
            f16x8 a0 = *(const f16x8*)(&As[bsel][0] + oa[0][kh]);
            f16x8 a1 = *(const f16x8*)(&As[bsel][0] + oa[1][kh]);
            f16x8 b0 = *(const f16x8*)(&Bs[bsel][0] + ob[0][kh]);
            f16x8 b1 = *(const f16x8*)(&Bs[bsel][0] + ob[1][kh]);
            acc[0][0] = MFMA32(a0, b0, acc[0][0]);
            acc[0][1] = MFMA32(a0, b1, acc[0][1]);
            acc[1][0] = MFMA32(a1, b0, acc[1][0]);
            acc[1][1] = MFMA32(a1, b1, acc[1][1]);
        }
    };

    stage(0, 0);
#pragma unroll 1
    for (int k0 = 0; k0 < DIM; k0 += 64) {
        __syncthreads();
        if (k0 + 32 < DIM) stage(1, k0 + 32);
        compute(0);
        __syncthreads();
        if (k0 + 64 < DIM) stage(0, k0 + 64);
        compute(1);
    }
    const int er = 4 * l5;
#pragma unroll
    for (int i = 0; i < 2; i++)
#pragma unroll
        for (int reg = 0; reg < 16; reg++) {
            int rloc = wr * 64 + i * 32 + er + 8 * (reg >> 2) + (reg & 3);
            int a = rowmap[rloc];
            if (a >= 0) {
#pragma unroll
                for (int j = 0; j < 2; j++) {
                    int cc = nt * 128 + wc * 64 + j * 32 + l31;
                    float v = acc[i][j][reg] + eb1[e * EHID + cc];
                    He[(size_t)a * EHID + cc] = (half_t)gelu_exact(v);
                }
            }
        }
}

// ---------------- expert GEMM2: Ye[a] = (He[a] @ ew2[e] + eb2[e]) * gate[a] ----------------
__global__ __launch_bounds__(256) void egemm2_kernel(
    const half_t* __restrict__ Hin,  // [2*NTOK][EHID]
    const half_t* __restrict__ W,    // [E][DIM][EHID]
    const float* __restrict__ eb2,
    const int* __restrict__ cnt, const int* __restrict__ aid,
    const float* __restrict__ gate,
    float* __restrict__ Ye)          // [2*NTOK][DIM]
{
    const int bid = blockIdx.x;
    const int e = bid >> 8, rem = bid & 255;
    const int mt = rem >> 2, nt = rem & 3;
    const int ne = cnt[e * 32];
    if (mt * 128 >= ne) return;
    __shared__ __align__(16) half_t As[2][128 * 32];
    __shared__ __align__(16) half_t Bs[2][128 * 32];
    __shared__ int rowmap[128];
    const int tid = threadIdx.x;
    if (tid < 128) {
        int slot = mt * 128 + tid;
        rowmap[tid] = (slot < ne) ? aid[e * NTOK + slot] : -1;
    }
    __syncthreads();
    const int lane = tid & 63, wid = tid >> 6;
    const int wr = wid >> 1, wc = wid & 1;
    const int l31 = lane & 31, l5 = lane >> 5;
    const int c0 = tid, c1 = tid + 256;
    const int r0 = c0 >> 2, s0 = (c0 & 3) ^ ((r0 >> 1) & 3);
    const int r1 = c1 >> 2, s1 = (c1 & 3) ^ ((r1 >> 1) & 3);
    const int a0r = rowmap[r0], a1r = rowmap[r1];
    const half_t* pa0 = Hin + (size_t)(a0r >= 0 ? a0r : 0) * EHID + s0 * 8;
    const half_t* pa1 = Hin + (size_t)(a1r >= 0 ? a1r : 0) * EHID + s1 * 8;
    const half_t* pb0 = W + (size_t)e * DIM * EHID + (size_t)(nt * 128 + r0) * EHID + s0 * 8;
    const half_t* pb1 = W + (size_t)e * DIM * EHID + (size_t)(nt * 128 + r1) * EHID + s1 * 8;

    int oa[2][2], ob[2][2];
#pragma unroll
    for (int i = 0; i < 2; i++)
#pragma unroll
        for (int kh = 0; kh < 2; kh++) {
            int ra = wr * 64 + i * 32 + l31;
            oa[i][kh] = ra * 32 + (((l5 + kh * 2) ^ ((ra >> 1) & 3)) << 3);
            int rb = wc * 64 + i * 32 + l31;
            ob[i][kh] = rb * 32 + (((l5 + kh * 2) ^ ((rb >> 1) & 3)) << 3);
        }
    f32x16 acc[2][2];
#pragma unroll
    for (int i = 0; i < 2; i++)
#pragma unroll
        for (int j = 0; j < 2; j++)
#pragma unroll
            for (int q = 0; q < 16; q++) acc[i][j][q] = 0.f;

    auto stage = [&](int bsel, int k0) {
        gl16(pa0 + k0, &As[bsel][c0 * 8]);
        gl16(pa1 + k0, &As[bsel][c1 * 8]);
        gl16(pb0 + k0, &Bs[bsel][c0 * 8]);
        gl16(pb1 + k0, &Bs[bsel][c1 * 8]);
    };
    auto compute = [&](int bsel) {
#pragma unroll
        for (int kh = 0; kh < 2; kh++) {
            f16x8 a0 = *(const f16x8*)(&As[bsel][0] + oa[0][kh]);
            f16x8 a1 = *(const f16x8*)(&As[bsel][0] + oa[1][kh]);
            f16x8 b0 = *(const f16x8*)(&Bs[bsel][0] + ob[0][kh]);
            f16x8 b1 = *(const f16x8*)(&Bs[bsel][0] + ob[1][kh]);
            acc[0][0] = MFMA32(a0, b0, acc[0][0]);
            acc[0][1] = MFMA32(a0, b1, acc[0][1]);
            acc[1][0] = MFMA32(a1, b0, acc[1][0]);
            acc[1][1] = MFMA32(a1, b1, acc[1][1]);
        }
    };

    stage(0, 0);
#pragma unroll 1
    for (int k0 = 0; k0 < EHID; k0 += 64) {
        __syncthreads();
        if (k0 + 32 < EHID) stage(1, k0 + 32);
        compute(0);
        __syncthreads();
        if (k0 + 64 < EHID) stage(0, k0 + 64);
        compute(1);
    }
    const int er = 4 * l5;
#pragma unroll
    for (int i = 0; i < 2; i++)
#pragma unroll
        for (int reg = 0; reg < 16; reg++) {
            int rloc = wr * 64 + i * 32 + er + 8 * (reg >> 2) + (reg & 3);
            int a = rowmap[rloc];
            if (a >= 0) {
                float gv = gate[a];
#pragma unroll
                for (int j = 0; j < 2; j++) {
                    int cc = nt * 128 + wc * 64 + j * 32 + l31;
                    float v = (acc[i][j][reg] + eb2[e * DIM + cc]) * gv;
                    Ye[(size_t)a * DIM + cc] = v;
                }
            }
        }
}

// ---------------- combine two expert outputs per token + final LN ----------------
__global__ __launch_bounds__(256) void combine_lnf_kernel(
    const float* __restrict__ Ye, const float* __restrict__ g, const float* __restrict__ b,
    float* __restrict__ out)
{
    const int t = blockIdx.x, tid = threadIdx.x;
    __shared__ float red[4];
    float2 y0 = reinterpret_cast<const float2*>(Ye + (size_t)(2 * t) * DIM)[tid];
    float2 y1 = reinterpret_cast<const float2*>(Ye + (size_t)(2 * t + 1) * DIM)[tid];
    float z0 = y0.x + y1.x, z1 = y0.y + y1.y;
    float mean = block_sum4(z0 + z1, red, tid) * (1.0f / DIM);
    float d0 = z0 - mean, d1 = z1 - mean;
    float var = block_sum4(d0 * d0 + d1 * d1, red, tid) * (1.0f / DIM);
    float rstd = rsqrtf(var + 1e-5f);
    int d = tid * 2;
    out[(size_t)t * DIM + d]     = d0 * rstd * g[d]     + b[d];
    out[(size_t)t * DIM + d + 1] = d1 * rstd * g[d + 1] + b[d + 1];
    if (t == 0 && tid == 0) out[(size_t)NTOK * DIM] = 0.f;  // aux_loss
}

extern "C" void kernel_launch(void* const* d_in, const int* in_sizes, int n_in,
                              void* d_out, int out_size, void* d_ws, size_t ws_size,
                              hipStream_t stream)
{
    (void)in_sizes; (void)n_in; (void)out_size; (void)ws_size;
    const float* x    = (const float*)d_in[0];
    const float* ln1g = (const float*)d_in[1];
    const float* ln1b = (const float*)d_in[2];
    const float* w1   = (const float*)d_in[3];
    const float* b1   = (const float*)d_in[4];
    const float* w2   = (const float*)d_in[5];
    const float* b2   = (const float*)d_in[6];
    const float* ln2g = (const float*)d_in[7];
    const float* ln2b = (const float*)d_in[8];
    const float* wrm  = (const float*)d_in[9];
    const float* ew1  = (const float*)d_in[10];
    const float* eb1  = (const float*)d_in[11];
    const float* ew2  = (const float*)d_in[12];
    const float* eb2  = (const float*)d_in[13];
    const float* lnfg = (const float*)d_in[14];
    const float* lnfb = (const float*)d_in[15];
    float* out = (float*)d_out;

    char* w = (char*)d_ws;
    size_t off = 0;
    auto take = [&](size_t bytes) {
        char* p = w + off;
        off += bytes;
        off = (off + 255) & ~(size_t)255;
        return p;
    };
    half_t* xh_h  = (half_t*)take((size_t)NTOK * DIM * 2);   // also split-K partial p1 (f32, 16MB)
    half_t* xh_l  = (half_t*)take((size_t)NTOK * DIM * 2);
    half_t* w1t_h = (half_t*)take((size_t)DIM * MHID * 2);
    half_t* w1t_l = (half_t*)take((size_t)DIM * MHID * 2);
    half_t* w2t_h = (half_t*)take((size_t)MHID * DIM * 2);
    half_t* w2t_l = (half_t*)take((size_t)MHID * DIM * 2);
    char*   big   = take((size_t)NTOK * MHID * 2 * 2);        // 64 MiB: a1 hi/lo, later He + Ye
    half_t* a1h   = (half_t*)big;
    half_t* a1l   = (half_t*)(big + (size_t)NTOK * MHID * 2);
    half_t* heh   = (half_t*)big;                              // alias (a1 dead after gemm8<0>)
    float*  yef   = (float*)(big + (size_t)NTOK * MHID * 2);   // alias
    float*  x3f   = (float*)take((size_t)NTOK * DIM * 4);      // split-K partial p0, then x3 f32
    half_t* x3h   = (half_t*)take((size_t)NTOK * DIM * 2);
    half_t* ew1t  = (half_t*)take((size_t)NEXP * DIM * EHID * 2);
    half_t* ew2t  = (half_t*)take((size_t)NEXP * EHID * DIM * 2);
    int*    cnt   = (int*)take(1024);                          // 8 experts, 128 B apart
    int*    aid   = (int*)take((size_t)NEXP * NTOK * 4);
    float*  gate  = (float*)take((size_t)NTOK * 2 * 4);

    float* p0 = x3f;
    float* p1 = (float*)xh_h;   // xh_h+xh_l = contiguous 16 MB, dead after gemm8<1>

    ln1_split_kernel<<<NTOK, 256, 0, stream>>>(x, ln1g, ln1b, xh_h, xh_l, cnt);
    transpose_all_kernel<<<10240, dim3(32, 8), 0, stream>>>(
        w1, w2, ew1, ew2, w1t_h, w1t_l, w2t_h, w2t_l, ew1t, ew2t);
    // MLP GEMM1: [8192x512] @ [512x2048], gelu, split out.  256x256 tile, 8 waves.
    gemm8_kernel<1, 2><<<dim3(NTOK / 256, MHID / 256, 1), 512, 0, stream>>>(
        xh_h, xh_l, w1t_h, w1t_l, b1, (float*)0, (float*)0, a1h, a1l, MHID, DIM, DIM);
    // MLP GEMM2: [8192x2048] @ [2048x512], 256x128 tile, split-K=2 raw partials
    gemm8_kernel<0, 1><<<dim3(NTOK / 256, DIM / 128, 2), 512, 0, stream>>>(
        a1h, a1l, w2t_h, w2t_l, (const float*)0, p0, p1, (half_t*)0, (half_t*)0, DIM, MHID, MHID / 2);
    resid_ln2_kernel<<<NTOK, 256, 0, stream>>>(x, p0, p1, b2, ln2g, ln2b, x3h);
    router_kernel<<<NTOK / RBLK, 256, 0, stream>>>(x3f, wrm, cnt, aid, gate);
    egemm1_kernel<<<NEXP * (NTOK / 128) * (EHID / 128), 256, 0, stream>>>(x3h, ew1t, eb1, cnt, aid, heh);
    egemm2_kernel<<<NEXP * (NTOK / 128) * (DIM / 128), 256, 0, stream>>>(heh, ew2t, eb2, cnt, aid, gate, yef);
    combine_lnf_kernel<<<NTOK, 256, 0, stream>>>(yef, lnfg, lnfb, out);
}

// Round 11
// 306.648 us; speedup vs baseline: 1.3286x; 1.0079x over previous
//
#include <hip/hip_runtime.h>

#define NTOK 8192
#define DIM  512
#define MHID 2048
#define EHID 1024
#define NEXP 8
#define RBLK 64   // tokens per router block

using half_t = _Float16;
typedef _Float16 f16x8 __attribute__((ext_vector_type(8)));
typedef float    f32x16 __attribute__((ext_vector_type(16)));

#define MFMA32(a, b, c) __builtin_amdgcn_mfma_f32_32x32x16_f16((a), (b), (c), 0, 0, 0)

typedef const __attribute__((address_space(1))) void* gas_ptr;
typedef __attribute__((address_space(3))) void*       las_ptr;
__device__ __forceinline__ void gl16(const void* g, void* l) {
    __builtin_amdgcn_global_load_lds((gas_ptr)g, (las_ptr)l, 16, 0, 0);
}

__device__ __forceinline__ float gelu_exact(float v) {
    return 0.5f * v * (1.0f + erff(v * 0.70710678118654752f));
}

// all-threads-return block sum over 4 waves (256 threads)
__device__ __forceinline__ float block_sum4(float v, float* red, int tid) {
#pragma unroll
    for (int off = 32; off; off >>= 1) v += __shfl_down(v, off);
    if ((tid & 63) == 0) red[tid >> 6] = v;
    __syncthreads();
    float r = red[0] + red[1] + red[2] + red[3];
    __syncthreads();
    return r;
}

// ---------------- LN1 + fp16 hi/lo split (+ folds cnt zeroing) ----------------
__global__ __launch_bounds__(256) void ln1_split_kernel(
    const float* __restrict__ x, const float* __restrict__ g, const float* __restrict__ b,
    half_t* __restrict__ xh, half_t* __restrict__ xl, int* __restrict__ cnt)
{
    const int row = blockIdx.x, tid = threadIdx.x;
    if (row == 0) cnt[tid] = 0;   // zero all 256 padded slots (8 experts * stride 32)
    __shared__ float red[4];
    const size_t base = (size_t)row * DIM;
    float2 v = reinterpret_cast<const float2*>(x + base)[tid];
    float mean = block_sum4(v.x + v.y, red, tid) * (1.0f / DIM);
    float d0 = v.x - mean, d1 = v.y - mean;
    float var = block_sum4(d0 * d0 + d1 * d1, red, tid) * (1.0f / DIM);
    float rstd = rsqrtf(var + 1e-5f);
    int d = tid * 2;
    float y0 = d0 * rstd * g[d]     + b[d];
    float y1 = d1 * rstd * g[d + 1] + b[d + 1];
    half_t h0 = (half_t)y0, h1 = (half_t)y1;
    xh[base + d] = h0;  xh[base + d + 1] = h1;
    xl[base + d]     = (half_t)(y0 - (float)h0);
    xl[base + d + 1] = (half_t)(y1 - (float)h1);
}

// ---- x2 = x + (p0+p1+b2) ; x3 = LN2(x2) + x2 ; write x3 (f32, over p0) + f16 ----
__global__ __launch_bounds__(256) void resid_ln2_kernel(
    const float* __restrict__ x, float* __restrict__ p0, const float* __restrict__ p1,
    const float* __restrict__ b2,
    const float* __restrict__ g, const float* __restrict__ b,
    half_t* __restrict__ x3h)
{
    const int row = blockIdx.x, tid = threadIdx.x;
    __shared__ float red[4];
    const size_t base = (size_t)row * DIM;
    float2 xv = reinterpret_cast<const float2*>(x + base)[tid];
    float2 h0 = reinterpret_cast<float2*>(p0 + base)[tid];
    float2 h1 = reinterpret_cast<const float2*>(p1 + base)[tid];
    float2 bb = reinterpret_cast<const float2*>(b2)[tid];
    float z0 = xv.x + h0.x + h1.x + bb.x, z1 = xv.y + h0.y + h1.y + bb.y;
    float mean = block_sum4(z0 + z1, red, tid) * (1.0f / DIM);
    float d0 = z0 - mean, d1 = z1 - mean;
    float var = block_sum4(d0 * d0 + d1 * d1, red, tid) * (1.0f / DIM);
    float rstd = rsqrtf(var + 1e-5f);
    int d = tid * 2;
    float y0 = d0 * rstd * g[d]     + b[d]     + z0;
    float y1 = d1 * rstd * g[d + 1] + b[d + 1] + z1;
    float2 o; o.x = y0; o.y = y1;
    reinterpret_cast<float2*>(p0 + base)[tid] = o;
    x3h[base + d]     = (half_t)y0;
    x3h[base + d + 1] = (half_t)y1;
}

// ---- ALL weight transposes in ONE launch: [R][C] -> [C][R], f16 (optional lo split) ----
__global__ void transpose_all_kernel(
    const float* __restrict__ w1, const float* __restrict__ w2,
    const float* __restrict__ ew1, const float* __restrict__ ew2,
    half_t* __restrict__ w1t_h, half_t* __restrict__ w1t_l,
    half_t* __restrict__ w2t_h, half_t* __restrict__ w2t_l,
    half_t* __restrict__ ew1t, half_t* __restrict__ ew2t)
{
    int bb = blockIdx.x;
    const float* in; half_t* oh; half_t* ol = (half_t*)0;
    int R, C, cx, cy; size_t mo = 0;
    if (bb < 1024)      { in = w1;  oh = w1t_h; ol = w1t_l; R = 512;  C = 2048; cx = bb & 63; cy = bb >> 6; }
    else if (bb < 2048) { bb -= 1024; in = w2;  oh = w2t_h; ol = w2t_l; R = 2048; C = 512; cx = bb & 15; cy = bb >> 4; }
    else if (bb < 6144) { bb -= 2048; int e = bb >> 9, r = bb & 511;
                          in = ew1; oh = ew1t; R = 512;  C = 1024; mo = (size_t)e * R * C; cx = r & 31; cy = r >> 5; }
    else                { bb -= 6144; int e = bb >> 9, r = bb & 511;
                          in = ew2; oh = ew2t; R = 1024; C = 512;  mo = (size_t)e * R * C; cx = r & 15; cy = r >> 4; }
    __shared__ float t[32][33];
    const int c0 = cx * 32, r0 = cy * 32;
    const int tx = threadIdx.x, ty = threadIdx.y;
    for (int i = ty; i < 32; i += 8) t[i][tx] = in[mo + (size_t)(r0 + i) * C + c0 + tx];
    __syncthreads();
    for (int i = ty; i < 32; i += 8) {
        float v = t[tx][i];
        size_t o = mo + (size_t)(c0 + i) * R + r0 + tx;
        half_t h = (half_t)v;
        oh[o] = h;
        if (ol) ol[o] = (half_t)(v - (float)h);
    }
}

// ======== split-3 f16 MFMA GEMM, 256-row tile, 8 waves, counted-vmcnt, 2 barriers/step ========
template <int EPI, int NREP>
__global__ __launch_bounds__(512, 2) void gemm8_kernel(
    const half_t* __restrict__ A0, const half_t* __restrict__ A1,
    const half_t* __restrict__ B0, const half_t* __restrict__ B1,
    const float* __restrict__ bias,
    float* __restrict__ Cf0, float* __restrict__ Cf1,
    half_t* __restrict__ Ch, half_t* __restrict__ Cl,
    int Nc, int K, int Ktile)
{
    constexpr int BN    = NREP * 128;
    constexpr int LOADS = 4 + 2 * NREP;            // 16B chunks staged per thread per K-step
    constexpr int TOT   = 16384 + NREP * 8192;     // half_t elems per LDS buffer
    __shared__ __align__(16) half_t lds[2 * TOT];

    const int m0 = blockIdx.x * 256, n0 = blockIdx.y * BN;
    const int kbeg = blockIdx.z * Ktile;
    float* Cf = blockIdx.z ? Cf1 : Cf0;
    const int tid = threadIdx.x;
    const int lane = tid & 63, wid = tid >> 6;
    const int wr = wid >> 2, wc = wid & 3;         // 2 x 4 wave grid
    const int l31 = lane & 31, l5 = lane >> 5;

    const half_t* gsrc[LOADS];
    {
        const half_t* A0p = A0 + (size_t)m0 * K + kbeg;
        const half_t* A1p = A1 + (size_t)m0 * K + kbeg;
        const half_t* B0p = B0 + (size_t)n0 * K + kbeg;
        const half_t* B1p = B1 + (size_t)n0 * K + kbeg;
#pragma unroll
        for (int i = 0; i < LOADS; i++) {
            int c = tid + 512 * i;
            const half_t* base; int cm;
            if (c < 1024)                  { base = A0p; cm = c; }
            else if (c < 2048)             { base = A1p; cm = c - 1024; }
            else if (c < 2048 + NREP * 512){ base = B0p; cm = c - 2048; }
            else                           { base = B1p; cm = c - 2048 - NREP * 512; }
            int r = cm >> 2, ss = (cm & 3) ^ ((r >> 1) & 3);
            gsrc[i] = base + (size_t)r * K + ss * 8;
        }
    }

    int oa[4][2], ob[NREP][2];
#pragma unroll
    for (int m = 0; m < 4; m++)
#pragma unroll
        for (int kh = 0; kh < 2; kh++) {
            int ra = wr * 128 + m * 32 + l31;
            oa[m][kh] = ra * 32 + (((l5 + 2 * kh) ^ ((ra >> 1) & 3)) << 3);
        }
#pragma unroll
    for (int n = 0; n < NREP; n++)
#pragma unroll
        for (int kh = 0; kh < 2; kh++) {
            int rb = wc * (NREP * 32) + n * 32 + l31;
            ob[n][kh] = rb * 32 + (((l5 + 2 * kh) ^ ((rb >> 1) & 3)) << 3);
        }

    f32x16 acc[4][NREP];
#pragma unroll
    for (int m = 0; m < 4; m++)
#pragma unroll
        for (int n = 0; n < NREP; n++)
#pragma unroll
            for (int q = 0; q < 16; q++) acc[m][n][q] = 0.f;

    auto stage = [&](int bsel, int kof) {
#pragma unroll
        for (int i = 0; i < LOADS; i++)
            gl16(gsrc[i] + kof, &lds[bsel * TOT + (tid + 512 * i) * 8]);
    };
    auto compute = [&](int p) {
        const half_t* buf = &lds[p ? TOT : 0];
        __builtin_amdgcn_s_setprio(1);
#pragma unroll
        for (int kh = 0; kh < 2; kh++) {
            f16x8 ah[4], al[4], bh[NREP], bl[NREP];
#pragma unroll
            for (int m = 0; m < 4; m++) {
                ah[m] = *(const f16x8*)(buf + oa[m][kh]);
                al[m] = *(const f16x8*)(buf + 8192 + oa[m][kh]);
            }
#pragma unroll
            for (int n = 0; n < NREP; n++) {
                bh[n] = *(const f16x8*)(buf + 16384 + ob[n][kh]);
                bl[n] = *(const f16x8*)(buf + 16384 + BN * 32 + ob[n][kh]);
            }
#pragma unroll
            for (int m = 0; m < 4; m++)
#pragma unroll
                for (int n = 0; n < NREP; n++) {
                    acc[m][n] = MFMA32(ah[m], bh[n], acc[m][n]);
                    acc[m][n] = MFMA32(al[m], bh[n], acc[m][n]);
                    acc[m][n] = MFMA32(ah[m], bl[n], acc[m][n]);
                }
        }
        __builtin_amdgcn_s_setprio(0);
    };

    const int nsteps = Ktile / 32;
    stage(0, 0);
#pragma unroll 1
    for (int s = 0; s < nsteps - 1; ++s) {
        stage((s + 1) & 1, (s + 1) * 32);
        if constexpr (NREP == 2) asm volatile("s_waitcnt vmcnt(8)" ::: "memory");
        else                     asm volatile("s_waitcnt vmcnt(6)" ::: "memory");
        __builtin_amdgcn_s_barrier();
        compute(s & 1);
        __builtin_amdgcn_s_barrier();
    }
    asm volatile("s_waitcnt vmcnt(0)" ::: "memory");
    __builtin_amdgcn_s_barrier();
    compute((nsteps - 1) & 1);

    const int er = 4 * l5;
#pragma unroll
    for (int m = 0; m < 4; m++)
#pragma unroll
        for (int n = 0; n < NREP; n++) {
            int cc = n0 + wc * (NREP * 32) + n * 32 + l31;
            float bv = (EPI == 1) ? bias[cc] : 0.f;
#pragma unroll
            for (int reg = 0; reg < 16; reg++) {
                int rr = m0 + wr * 128 + m * 32 + er + 8 * (reg >> 2) + (reg & 3);
                float v = acc[m][n][reg] + bv;
                size_t o = (size_t)rr * Nc + cc;
                if (EPI == 1) {
                    float ge = gelu_exact(v);
                    half_t h = (half_t)ge;
                    Ch[o] = h;
                    Cl[o] = (half_t)(ge - (float)h);
                } else {
                    Cf[o] = v;
                }
            }
        }
}

// ---------------- router ----------------
__global__ __launch_bounds__(256) void router_kernel(
    const float* __restrict__ x3, const float* __restrict__ wrm,
    int* __restrict__ cnt, int* __restrict__ aid, float* __restrict__ gate)
{
    __shared__ float wl[NEXP][DIM];
    __shared__ int   texp[RBLK * 2];
    __shared__ float tgate[RBLK * 2];
    __shared__ int   lslot[RBLK * 2];
    __shared__ int   lcnt[NEXP], lbase[NEXP];
    const int tid = threadIdx.x;
    for (int i = tid; i < NEXP * DIM / 4; i += 256)
        reinterpret_cast<float4*>(&wl[0][0])[i] = reinterpret_cast<const float4*>(wrm)[i];
    if (tid < NEXP) lcnt[tid] = 0;
    __syncthreads();
    const int w = tid >> 6, lane = tid & 63;
#pragma unroll 1
    for (int t = 0; t < RBLK / 4; ++t) {
        const int lt = w * (RBLK / 4) + t;
        const int token = blockIdx.x * RBLK + lt;
        const float* xr = x3 + (size_t)token * DIM;
        float a[NEXP];
#pragma unroll
        for (int e = 0; e < NEXP; e++) a[e] = 0.f;
#pragma unroll
        for (int d0 = 0; d0 < DIM; d0 += 64) {
            float xv = xr[d0 + lane];
#pragma unroll
            for (int e = 0; e < NEXP; e++) a[e] += xv * wl[e][d0 + lane];
        }
#pragma unroll
        for (int e = 0; e < NEXP; e++)
#pragma unroll
            for (int off = 32; off; off >>= 1) a[e] += __shfl_xor(a[e], off);
        if (lane == 0) {
            int i1 = 0; float v1 = a[0];
#pragma unroll
            for (int e = 1; e < NEXP; e++) if (a[e] > v1) { v1 = a[e]; i1 = e; }
            int i2 = -1; float v2 = -3.4e38f;
#pragma unroll
            for (int e = 0; e < NEXP; e++) if (e != i1 && a[e] > v2) { v2 = a[e]; i2 = e; }
            float e2 = expf(v2 - v1);
            float g1 = 1.0f / (1.0f + e2);
            texp[lt * 2]      = i1; tgate[lt * 2]      = g1;
            texp[lt * 2 + 1]  = i2; tgate[lt * 2 + 1]  = 1.0f - g1;
        }
    }
    __syncthreads();
    if (tid < RBLK * 2) lslot[tid] = atomicAdd(&lcnt[texp[tid]], 1);
    __syncthreads();
    if (tid < NEXP) lbase[tid] = atomicAdd(&cnt[tid * 32], lcnt[tid]);
    __syncthreads();
    if (tid < RBLK * 2) {
        const int e = texp[tid];
        const int asg = blockIdx.x * (RBLK * 2) + tid;   // token*2 + k
        aid[e * NTOK + lbase[e] + lslot[tid]] = asg;
        gate[asg] = tgate[tid];
    }
}

// ======== expert GEMMs, 8-wave 256-row-tile counted-vmcnt structure ========
// BM=256 (rowmap-gathered), BN=128, 8 waves 4(M)x2(N), per-wave 64x64, BK=32.
// LDS/buffer: A 256x32 (16KB) + B 128x32 (8KB) = 24KB; x2 dbuf = 48KB -> 3 blocks/CU.
// 3 gl16/thread/step; counted vmcnt(3); 2 barriers/step.
// EG=1: He[a] = gelu(X[a>>1] @ W^T + eb).  EG=2: Ye[a] = (Hin[a] @ W^T + eb) * gate[a].
template <int EG, int KDIM, int AROWSHIFT>
__global__ __launch_bounds__(512, 2) void egemm8_kernel(
    const half_t* __restrict__ Ain,   // EG1: X [NTOK][DIM]; EG2: Hin [2*NTOK][EHID]
    const half_t* __restrict__ W,     // EG1: [E][EHID][DIM]; EG2: [E][DIM][EHID]
    const float* __restrict__ ebias,
    const int* __restrict__ cnt, const int* __restrict__ aid,
    const float* __restrict__ gate,
    half_t* __restrict__ Oh,          // EG1 out
    float* __restrict__ Of,           // EG2 out
    int Nc)                           // EG1: EHID; EG2: DIM
{
    const int ntPerE = Nc / 128;                 // 8 (EG1) or 4 (EG2)
    const int bid = blockIdx.x;
    const int e   = bid / (32 * ntPerE);
    const int rem = bid % (32 * ntPerE);
    const int mt  = rem / ntPerE, nt = rem % ntPerE;
    const int ne  = cnt[e * 32];
    if (mt * 256 >= ne) return;

    constexpr int TOT = 8192 + 4096;             // elems per buffer: A 256x32, B 128x32
    __shared__ __align__(16) half_t lds[2 * TOT];
    __shared__ int rowmap[256];
    const int tid = threadIdx.x;
    {
        int slot = mt * 256 + tid;
        if (tid < 256) rowmap[tid] = (slot < ne) ? aid[e * NTOK + slot] : -1;
    }
    __syncthreads();

    const int lane = tid & 63, wid = tid >> 6;
    const int wr = wid >> 1, wc = wid & 1;       // 4 x 2 wave grid
    const int l31 = lane & 31, l5 = lane >> 5;

    // staging: chunks c = tid + 512*i, i<3.  c<1024 -> A (row c>>2), else B.
    const half_t* gsrc[3];
    const half_t* Wb = W + (size_t)e * Nc * KDIM;
#pragma unroll
    for (int i = 0; i < 3; i++) {
        int c = tid + 512 * i;
        if (c < 1024) {
            int r = c >> 2, ss = (c & 3) ^ ((r >> 1) & 3);
            int a = rowmap[r];
            gsrc[i] = Ain + (size_t)(a >= 0 ? (a >> AROWSHIFT) : 0) * KDIM + ss * 8;
        } else {
            int cb = c - 1024;
            int r = cb >> 2, ss = (cb & 3) ^ ((r >> 1) & 3);
            gsrc[i] = Wb + (size_t)(nt * 128 + r) * KDIM + ss * 8;
        }
    }

    int oa[2][2], ob[2][2];
#pragma unroll
    for (int m = 0; m < 2; m++)
#pragma unroll
        for (int kh = 0; kh < 2; kh++) {
            int ra = wr * 64 + m * 32 + l31;
            oa[m][kh] = ra * 32 + (((l5 + 2 * kh) ^ ((ra >> 1) & 3)) << 3);
        }
#pragma unroll
    for (int n = 0; n < 2; n++)
#pragma unroll
        for (int kh = 0; kh < 2; kh++) {
            int rb = wc * 64 + n * 32 + l31;
            ob[n][kh] = 8192 + rb * 32 + (((l5 + 2 * kh) ^ ((rb >> 1) & 3)) << 3);
        }

    f32x16 acc[2][2];
#pragma unroll
    for (int m = 0; m < 2; m++)
#pragma unroll
        for (int n = 0; n < 2; n++)
#pragma unroll
            for (int q = 0; q < 16; q++) acc[m][n][q] = 0.f;

    auto stage = [&](int bsel, int kof) {
#pragma unroll
        for (int i = 0; i < 3; i++)
            gl16(gsrc[i] + kof, &lds[bsel * TOT + (tid + 512 * i) * 8]);
    };
    auto compute = [&](int p) {
        const half_t* buf = &lds[p ? TOT : 0];
        __builtin_amdgcn_s_setprio(1);
#pragma unroll
        for (int kh = 0; kh < 2; kh++) {
            f16x8 a0 = *(const f16x8*)(buf + oa[0][kh]);
            f16x8 a1 = *(const f16x8*)(buf + oa[1][kh]);
            f16x8 b0 = *(const f16x8*)(buf + ob[0][kh]);
            f16x8 b1 = *(const f16x8*)(buf + ob[1][kh]);
            acc[0][0] = MFMA32(a0, b0, acc[0][0]);
            acc[0][1] = MFMA32(a0, b1, acc[0][1]);
            acc[1][0] = MFMA32(a1, b0, acc[1][0]);
            acc[1][1] = MFMA32(a1, b1, acc[1][1]);
        }
        __builtin_amdgcn_s_setprio(0);
    };

    const int nsteps = KDIM / 32;
    stage(0, 0);
#pragma unroll 1
    for (int s = 0; s < nsteps - 1; ++s) {
        stage((s + 1) & 1, (s + 1) * 32);
        asm volatile("s_waitcnt vmcnt(3)" ::: "memory");
        __builtin_amdgcn_s_barrier();
        compute(s & 1);
        __builtin_amdgcn_s_barrier();
    }
    asm volatile("s_waitcnt vmcnt(0)" ::: "memory");
    __builtin_amdgcn_s_barrier();
    compute((nsteps - 1) & 1);

    const int er = 4 * l5;
#pragma unroll
    for (int m = 0; m < 2; m++)
#pragma unroll
        for (int reg = 0; reg < 16; reg++) {
            int rloc = wr * 64 + m * 32 + er + 8 * (reg >> 2) + (reg & 3);
            int a = rowmap[rloc];
            if (a >= 0) {
#pragma unroll
                for (int n = 0; n < 2; n++) {
                    int cc = nt * 128 + wc * 64 + n * 32 + l31;
                    float v = acc[m][n][reg] + ebias[e * Nc + cc];
                    if (EG == 1) {
                        Oh[(size_t)a * Nc + cc] = (half_t)gelu_exact(v);
                    } else {
                        Of[(size_t)a * Nc + cc] = v * gate[a];
                    }
                }
            }
        }
}

// ---------------- combine two expert outputs per token + final LN ----------------
__global__ __launch_bounds__(256) void combine_lnf_kernel(
    const float* __restrict__ Ye, const float* __restrict__ g, const float* __restrict__ b,
    float* __restrict__ out)
{
    const int t = blockIdx.x, tid = threadIdx.x;
    __shared__ float red[4];
    float2 y0 = reinterpret_cast<const float2*>(Ye + (size_t)(2 * t) * DIM)[tid];
    float2 y1 = reinterpret_cast<const float2*>(Ye + (size_t)(2 * t + 1) * DIM)[tid];
    float z0 = y0.x + y1.x, z1 = y0.y + y1.y;
    float mean = block_sum4(z0 + z1, red, tid) * (1.0f / DIM);
    float d0 = z0 - mean, d1 = z1 - mean;
    float var = block_sum4(d0 * d0 + d1 * d1, red, tid) * (1.0f / DIM);
    float rstd = rsqrtf(var + 1e-5f);
    int d = tid * 2;
    out[(size_t)t * DIM + d]     = d0 * rstd * g[d]     + b[d];
    out[(size_t)t * DIM + d + 1] = d1 * rstd * g[d + 1] + b[d + 1];
    if (t == 0 && tid == 0) out[(size_t)NTOK * DIM] = 0.f;  // aux_loss
}

extern "C" void kernel_launch(void* const* d_in, const int* in_sizes, int n_in,
                              void* d_out, int out_size, void* d_ws, size_t ws_size,
                              hipStream_t stream)
{
    (void)in_sizes; (void)n_in; (void)out_size; (void)ws_size;
    const float* x    = (const float*)d_in[0];
    const float* ln1g = (const float*)d_in[1];
    const float* ln1b = (const float*)d_in[2];
    const float* w1   = (const float*)d_in[3];
    const float* b1   = (const float*)d_in[4];
    const float* w2   = (const float*)d_in[5];
    const float* b2   = (const float*)d_in[6];
    const float* ln2g = (const float*)d_in[7];
    const float* ln2b = (const float*)d_in[8];
    const float* wrm  = (const float*)d_in[9];
    const float* ew1  = (const float*)d_in[10];
    const float* eb1  = (const float*)d_in[11];
    const float* ew2  = (const float*)d_in[12];
    const float* eb2  = (const float*)d_in[13];
    const float* lnfg = (const float*)d_in[14];
    const float* lnfb = (const float*)d_in[15];
    float* out = (float*)d_out;

    char* w = (char*)d_ws;
    size_t off = 0;
    auto take = [&](size_t bytes) {
        char* p = w + off;
        off += bytes;
        off = (off + 255) & ~(size_t)255;
        return p;
    };
    half_t* xh_h  = (half_t*)take((size_t)NTOK * DIM * 2);   // also split-K partial p1 (f32, 16MB)
    half_t* xh_l  = (half_t*)take((size_t)NTOK * DIM * 2);
    half_t* w1t_h = (half_t*)take((size_t)DIM * MHID * 2);
    half_t* w1t_l = (half_t*)take((size_t)DIM * MHID * 2);
    half_t* w2t_h = (half_t*)take((size_t)MHID * DIM * 2);
    half_t* w2t_l = (half_t*)take((size_t)MHID * DIM * 2);
    char*   big   = take((size_t)NTOK * MHID * 2 * 2);        // 64 MiB: a1 hi/lo, later He + Ye
    half_t* a1h   = (half_t*)big;
    half_t* a1l   = (half_t*)(big + (size_t)NTOK * MHID * 2);
    half_t* heh   = (half_t*)big;                              // alias (a1 dead after gemm8<0>)
    float*  yef   = (float*)(big + (size_t)NTOK * MHID * 2);   // alias
    float*  x3f   = (float*)take((size_t)NTOK * DIM * 4);      // split-K partial p0, then x3 f32
    half_t* x3h   = (half_t*)take((size_t)NTOK * DIM * 2);
    half_t* ew1t  = (half_t*)take((size_t)NEXP * DIM * EHID * 2);
    half_t* ew2t  = (half_t*)take((size_t)NEXP * EHID * DIM * 2);
    int*    cnt   = (int*)take(1024);                          // 8 experts, 128 B apart
    int*    aid   = (int*)take((size_t)NEXP * NTOK * 4);
    float*  gate  = (float*)take((size_t)NTOK * 2 * 4);

    float* p0 = x3f;
    float* p1 = (float*)xh_h;   // xh_h+xh_l = contiguous 16 MB, dead after gemm8<1>

    ln1_split_kernel<<<NTOK, 256, 0, stream>>>(x, ln1g, ln1b, xh_h, xh_l, cnt);
    transpose_all_kernel<<<10240, dim3(32, 8), 0, stream>>>(
        w1, w2, ew1, ew2, w1t_h, w1t_l, w2t_h, w2t_l, ew1t, ew2t);
    // MLP GEMM1: [8192x512] @ [512x2048], gelu, split out.  256x256 tile, 8 waves.
    gemm8_kernel<1, 2><<<dim3(NTOK / 256, MHID / 256, 1), 512, 0, stream>>>(
        xh_h, xh_l, w1t_h, w1t_l, b1, (float*)0, (float*)0, a1h, a1l, MHID, DIM, DIM);
    // MLP GEMM2: [8192x2048] @ [2048x512], 256x128 tile, split-K=2 raw partials
    gemm8_kernel<0, 1><<<dim3(NTOK / 256, DIM / 128, 2), 512, 0, stream>>>(
        a1h, a1l, w2t_h, w2t_l, (const float*)0, p0, p1, (half_t*)0, (half_t*)0, DIM, MHID, MHID / 2);
    resid_ln2_kernel<<<NTOK, 256, 0, stream>>>(x, p0, p1, b2, ln2g, ln2b, x3h);
    router_kernel<<<NTOK / RBLK, 256, 0, stream>>>(x3f, wrm, cnt, aid, gate);
    // expert GEMM1: 8 experts x 32 m-tiles x 8 n-tiles, 256-row rowmap tiles, 8 waves
    egemm8_kernel<1, DIM, 1><<<NEXP * 32 * (EHID / 128), 512, 0, stream>>>(
        x3h, ew1t, eb1, cnt, aid, (const float*)0, heh, (float*)0, EHID);
    // expert GEMM2: 8 experts x 32 m-tiles x 4 n-tiles
    egemm8_kernel<2, EHID, 0><<<NEXP * 32 * (DIM / 128), 512, 0, stream>>>(
        heh, ew2t, eb2, cnt, aid, gate, (half_t*)0, yef, DIM);
    combine_lnf_kernel<<<NTOK, 256, 0, stream>>>(yef, lnfg, lnfb, out);
}

// Round 12
// 304.251 us; speedup vs baseline: 1.3391x; 1.0079x over previous
//
#include <hip/hip_runtime.h>

#define NTOK 8192
#define DIM  512
#define MHID 2048
#define EHID 1024
#define NEXP 8
#define RBLK 64   // tokens per router block

using half_t = _Float16;
typedef _Float16 f16x8 __attribute__((ext_vector_type(8)));
typedef float    f32x16 __attribute__((ext_vector_type(16)));

#define MFMA32(a, b, c) __builtin_amdgcn_mfma_f32_32x32x16_f16((a), (b), (c), 0, 0, 0)

typedef const __attribute__((address_space(1))) void* gas_ptr;
typedef __attribute__((address_space(3))) void*       las_ptr;
__device__ __forceinline__ void gl16(const void* g, void* l) {
    __builtin_amdgcn_global_load_lds((gas_ptr)g, (las_ptr)l, 16, 0, 0);
}

__device__ __forceinline__ float gelu_exact(float v) {
    return 0.5f * v * (1.0f + erff(v * 0.70710678118654752f));
}

// all-threads-return block sum over 4 waves (256 threads)
__device__ __forceinline__ float block_sum4(float v, float* red, int tid) {
#pragma unroll
    for (int off = 32; off; off >>= 1) v += __shfl_down(v, off);
    if ((tid & 63) == 0) red[tid >> 6] = v;
    __syncthreads();
    float r = red[0] + red[1] + red[2] + red[3];
    __syncthreads();
    return r;
}

// ---------------- LN1 + fp16 hi/lo split (+ folds cnt zeroing) ----------------
__global__ __launch_bounds__(256) void ln1_split_kernel(
    const float* __restrict__ x, const float* __restrict__ g, const float* __restrict__ b,
    half_t* __restrict__ xh, half_t* __restrict__ xl, int* __restrict__ cnt)
{
    const int row = blockIdx.x, tid = threadIdx.x;
    if (row == 0) cnt[tid] = 0;   // zero all 256 padded slots (8 experts * stride 32)
    __shared__ float red[4];
    const size_t base = (size_t)row * DIM;
    float2 v = reinterpret_cast<const float2*>(x + base)[tid];
    float mean = block_sum4(v.x + v.y, red, tid) * (1.0f / DIM);
    float d0 = v.x - mean, d1 = v.y - mean;
    float var = block_sum4(d0 * d0 + d1 * d1, red, tid) * (1.0f / DIM);
    float rstd = rsqrtf(var + 1e-5f);
    int d = tid * 2;
    float y0 = d0 * rstd * g[d]     + b[d];
    float y1 = d1 * rstd * g[d + 1] + b[d + 1];
    half_t h0 = (half_t)y0, h1 = (half_t)y1;
    xh[base + d] = h0;  xh[base + d + 1] = h1;
    xl[base + d]     = (half_t)(y0 - (float)h0);
    xl[base + d + 1] = (half_t)(y1 - (float)h1);
}

// ---- x2 = x + (p0+p1+b2) ; x3 = LN2(x2) + x2 ; write x3 (f32, over p0) + f16 ----
__global__ __launch_bounds__(256) void resid_ln2_kernel(
    const float* __restrict__ x, float* __restrict__ p0, const float* __restrict__ p1,
    const float* __restrict__ b2,
    const float* __restrict__ g, const float* __restrict__ b,
    half_t* __restrict__ x3h)
{
    const int row = blockIdx.x, tid = threadIdx.x;
    __shared__ float red[4];
    const size_t base = (size_t)row * DIM;
    float2 xv = reinterpret_cast<const float2*>(x + base)[tid];
    float2 h0 = reinterpret_cast<float2*>(p0 + base)[tid];
    float2 h1 = reinterpret_cast<const float2*>(p1 + base)[tid];
    float2 bb = reinterpret_cast<const float2*>(b2)[tid];
    float z0 = xv.x + h0.x + h1.x + bb.x, z1 = xv.y + h0.y + h1.y + bb.y;
    float mean = block_sum4(z0 + z1, red, tid) * (1.0f / DIM);
    float d0 = z0 - mean, d1 = z1 - mean;
    float var = block_sum4(d0 * d0 + d1 * d1, red, tid) * (1.0f / DIM);
    float rstd = rsqrtf(var + 1e-5f);
    int d = tid * 2;
    float y0 = d0 * rstd * g[d]     + b[d]     + z0;
    float y1 = d1 * rstd * g[d + 1] + b[d + 1] + z1;
    float2 o; o.x = y0; o.y = y1;
    reinterpret_cast<float2*>(p0 + base)[tid] = o;
    x3h[base + d]     = (half_t)y0;
    x3h[base + d + 1] = (half_t)y1;
}

// ---- ALL weight transposes in ONE launch: [R][C] -> [C][R], f16 (optional lo split) ----
__global__ void transpose_all_kernel(
    const float* __restrict__ w1, const float* __restrict__ w2,
    const float* __restrict__ ew1, const float* __restrict__ ew2,
    half_t* __restrict__ w1t_h, half_t* __restrict__ w1t_l,
    half_t* __restrict__ w2t_h, half_t* __restrict__ w2t_l,
    half_t* __restrict__ ew1t, half_t* __restrict__ ew2t)
{
    int bb = blockIdx.x;
    const float* in; half_t* oh; half_t* ol = (half_t*)0;
    int R, C, cx, cy; size_t mo = 0;
    if (bb < 1024)      { in = w1;  oh = w1t_h; ol = w1t_l; R = 512;  C = 2048; cx = bb & 63; cy = bb >> 6; }
    else if (bb < 2048) { bb -= 1024; in = w2;  oh = w2t_h; ol = w2t_l; R = 2048; C = 512; cx = bb & 15; cy = bb >> 4; }
    else if (bb < 6144) { bb -= 2048; int e = bb >> 9, r = bb & 511;
                          in = ew1; oh = ew1t; R = 512;  C = 1024; mo = (size_t)e * R * C; cx = r & 31; cy = r >> 5; }
    else                { bb -= 6144; int e = bb >> 9, r = bb & 511;
                          in = ew2; oh = ew2t; R = 1024; C = 512;  mo = (size_t)e * R * C; cx = r & 15; cy = r >> 4; }
    __shared__ float t[32][33];
    const int c0 = cx * 32, r0 = cy * 32;
    const int tx = threadIdx.x, ty = threadIdx.y;
    for (int i = ty; i < 32; i += 8) t[i][tx] = in[mo + (size_t)(r0 + i) * C + c0 + tx];
    __syncthreads();
    for (int i = ty; i < 32; i += 8) {
        float v = t[tx][i];
        size_t o = mo + (size_t)(c0 + i) * R + r0 + tx;
        half_t h = (half_t)v;
        oh[o] = h;
        if (ol) ol[o] = (half_t)(v - (float)h);
    }
}

// ======== split-3 f16 MFMA GEMM, 256-row tile, 8 waves ========
// FINE=0: 2-barrier-per-K-step counted-vmcnt structure (r9).
// FINE=1 (NREP==2 only): m201-style phase discipline — 4 phases/K-step of 12 MFMA
// each (phase = kh x m-half); each phase issues its ds_reads (+ P0/P1: 4 gl16 of
// tile s+1) BEFORE its barrier, then lgkmcnt(0)+sched_barrier(0)+setprio around the
// MFMA burst, then a closing barrier.  vmcnt(0) once per step start (only tile s in
// flight there; issued a full step earlier).  B-frags register-cached across m-halves.
template <int EPI, int NREP, int FINE>
__global__ __launch_bounds__(512, 2) void gemm8_kernel(
    const half_t* __restrict__ A0, const half_t* __restrict__ A1,
    const half_t* __restrict__ B0, const half_t* __restrict__ B1,
    const float* __restrict__ bias,
    float* __restrict__ Cf0, float* __restrict__ Cf1,
    half_t* __restrict__ Ch, half_t* __restrict__ Cl,
    int Nc, int K, int Ktile)
{
    constexpr int BN    = NREP * 128;
    constexpr int LOADS = 4 + 2 * NREP;            // 16B chunks staged per thread per K-step
    constexpr int TOT   = 16384 + NREP * 8192;     // half_t elems per LDS buffer
    __shared__ __align__(16) half_t lds[2 * TOT];

    const int m0 = blockIdx.x * 256, n0 = blockIdx.y * BN;
    const int kbeg = blockIdx.z * Ktile;
    float* Cf = blockIdx.z ? Cf1 : Cf0;
    const int tid = threadIdx.x;
    const int lane = tid & 63, wid = tid >> 6;
    const int wr = wid >> 2, wc = wid & 3;         // 2 x 4 wave grid
    const int l31 = lane & 31, l5 = lane >> 5;

    const half_t* gsrc[LOADS];
    {
        const half_t* A0p = A0 + (size_t)m0 * K + kbeg;
        const half_t* A1p = A1 + (size_t)m0 * K + kbeg;
        const half_t* B0p = B0 + (size_t)n0 * K + kbeg;
        const half_t* B1p = B1 + (size_t)n0 * K + kbeg;
#pragma unroll
        for (int i = 0; i < LOADS; i++) {
            int c = tid + 512 * i;
            const half_t* base; int cm;
            if (c < 1024)                  { base = A0p; cm = c; }
            else if (c < 2048)             { base = A1p; cm = c - 1024; }
            else if (c < 2048 + NREP * 512){ base = B0p; cm = c - 2048; }
            else                           { base = B1p; cm = c - 2048 - NREP * 512; }
            int r = cm >> 2, ss = (cm & 3) ^ ((r >> 1) & 3);
            gsrc[i] = base + (size_t)r * K + ss * 8;
        }
    }

    int oa[4][2], ob[NREP][2];
#pragma unroll
    for (int m = 0; m < 4; m++)
#pragma unroll
        for (int kh = 0; kh < 2; kh++) {
            int ra = wr * 128 + m * 32 + l31;
            oa[m][kh] = ra * 32 + (((l5 + 2 * kh) ^ ((ra >> 1) & 3)) << 3);
        }
#pragma unroll
    for (int n = 0; n < NREP; n++)
#pragma unroll
        for (int kh = 0; kh < 2; kh++) {
            int rb = wc * (NREP * 32) + n * 32 + l31;
            ob[n][kh] = rb * 32 + (((l5 + 2 * kh) ^ ((rb >> 1) & 3)) << 3);
        }

    f32x16 acc[4][NREP];
#pragma unroll
    for (int m = 0; m < 4; m++)
#pragma unroll
        for (int n = 0; n < NREP; n++)
#pragma unroll
            for (int q = 0; q < 16; q++) acc[m][n][q] = 0.f;

    auto stage = [&](int bsel, int kof) {
#pragma unroll
        for (int i = 0; i < LOADS; i++)
            gl16(gsrc[i] + kof, &lds[bsel * TOT + (tid + 512 * i) * 8]);
    };

    const int nsteps = Ktile / 32;

    if constexpr (FINE && NREP == 2) {
        stage(0, 0);
#pragma unroll 1
        for (int s = 0; s < nsteps; ++s) {
            const half_t* buf = &lds[(s & 1) ? TOT : 0];
            const int nxt = (s + 1) & 1;
            const bool more = (s + 1) < nsteps;
            const int kofn = (s + 1) * 32;
            asm volatile("s_waitcnt vmcnt(0)" ::: "memory");   // tile s landed (sole in-flight)
            __builtin_amdgcn_s_barrier();
            f16x8 bh[2], bl[2];
#pragma unroll
            for (int kh = 0; kh < 2; kh++) {
#pragma unroll
                for (int mh = 0; mh < 2; mh++) {
                    // ---- phase (kh, mh): issue staging + ds_reads BEFORE barrier ----
                    if (more && kh == 0) {     // P0: A-chunks, P1: B-chunks of tile s+1
#pragma unroll
                        for (int i = 0; i < 4; i++) {
                            int c = mh * 4 + i;
                            gl16(gsrc[c] + kofn, &lds[nxt * TOT + (tid + 512 * c) * 8]);
                        }
                    }
                    f16x8 ah[2], al[2];
#pragma unroll
                    for (int m = 0; m < 2; m++) {
                        ah[m] = *(const f16x8*)(buf + oa[mh * 2 + m][kh]);
                        al[m] = *(const f16x8*)(buf + 8192 + oa[mh * 2 + m][kh]);
                    }
                    if (mh == 0) {
#pragma unroll
                        for (int n = 0; n < 2; n++) {
                            bh[n] = *(const f16x8*)(buf + 16384 + ob[n][kh]);
                            bl[n] = *(const f16x8*)(buf + 16384 + BN * 32 + ob[n][kh]);
                        }
                    }
                    __builtin_amdgcn_s_barrier();
                    asm volatile("s_waitcnt lgkmcnt(0)" ::: "memory");
                    __builtin_amdgcn_sched_barrier(0);
                    __builtin_amdgcn_s_setprio(1);
#pragma unroll
                    for (int m = 0; m < 2; m++)
#pragma unroll
                        for (int n = 0; n < 2; n++) {
                            acc[mh * 2 + m][n] = MFMA32(ah[m], bh[n], acc[mh * 2 + m][n]);
                            acc[mh * 2 + m][n] = MFMA32(al[m], bh[n], acc[mh * 2 + m][n]);
                            acc[mh * 2 + m][n] = MFMA32(ah[m], bl[n], acc[mh * 2 + m][n]);
                        }
                    __builtin_amdgcn_s_setprio(0);
                    __builtin_amdgcn_s_barrier();
                }
            }
        }
    } else {
        auto compute = [&](int p) {
            const half_t* buf = &lds[p ? TOT : 0];
            __builtin_amdgcn_s_setprio(1);
#pragma unroll
            for (int kh = 0; kh < 2; kh++) {
                f16x8 ah[4], al[4], bh[NREP], bl[NREP];
#pragma unroll
                for (int m = 0; m < 4; m++) {
                    ah[m] = *(const f16x8*)(buf + oa[m][kh]);
                    al[m] = *(const f16x8*)(buf + 8192 + oa[m][kh]);
                }
#pragma unroll
                for (int n = 0; n < NREP; n++) {
                    bh[n] = *(const f16x8*)(buf + 16384 + ob[n][kh]);
                    bl[n] = *(const f16x8*)(buf + 16384 + BN * 32 + ob[n][kh]);
                }
#pragma unroll
                for (int m = 0; m < 4; m++)
#pragma unroll
                    for (int n = 0; n < NREP; n++) {
                        acc[m][n] = MFMA32(ah[m], bh[n], acc[m][n]);
                        acc[m][n] = MFMA32(al[m], bh[n], acc[m][n]);
                        acc[m][n] = MFMA32(ah[m], bl[n], acc[m][n]);
                    }
            }
            __builtin_amdgcn_s_setprio(0);
        };
        stage(0, 0);
#pragma unroll 1
        for (int s = 0; s < nsteps - 1; ++s) {
            stage((s + 1) & 1, (s + 1) * 32);
            if constexpr (NREP == 2) asm volatile("s_waitcnt vmcnt(8)" ::: "memory");
            else                     asm volatile("s_waitcnt vmcnt(6)" ::: "memory");
            __builtin_amdgcn_s_barrier();
            compute(s & 1);
            __builtin_amdgcn_s_barrier();
        }
        asm volatile("s_waitcnt vmcnt(0)" ::: "memory");
        __builtin_amdgcn_s_barrier();
        compute((nsteps - 1) & 1);
    }

    const int er = 4 * l5;
#pragma unroll
    for (int m = 0; m < 4; m++)
#pragma unroll
        for (int n = 0; n < NREP; n++) {
            int cc = n0 + wc * (NREP * 32) + n * 32 + l31;
            float bv = (EPI == 1) ? bias[cc] : 0.f;
#pragma unroll
            for (int reg = 0; reg < 16; reg++) {
                int rr = m0 + wr * 128 + m * 32 + er + 8 * (reg >> 2) + (reg & 3);
                float v = acc[m][n][reg] + bv;
                size_t o = (size_t)rr * Nc + cc;
                if (EPI == 1) {
                    float ge = gelu_exact(v);
                    half_t h = (half_t)ge;
                    Ch[o] = h;
                    Cl[o] = (half_t)(ge - (float)h);
                } else {
                    Cf[o] = v;
                }
            }
        }
}

// ---------------- router ----------------
__global__ __launch_bounds__(256) void router_kernel(
    const float* __restrict__ x3, const float* __restrict__ wrm,
    int* __restrict__ cnt, int* __restrict__ aid, float* __restrict__ gate)
{
    __shared__ float wl[NEXP][DIM];
    __shared__ int   texp[RBLK * 2];
    __shared__ float tgate[RBLK * 2];
    __shared__ int   lslot[RBLK * 2];
    __shared__ int   lcnt[NEXP], lbase[NEXP];
    const int tid = threadIdx.x;
    for (int i = tid; i < NEXP * DIM / 4; i += 256)
        reinterpret_cast<float4*>(&wl[0][0])[i] = reinterpret_cast<const float4*>(wrm)[i];
    if (tid < NEXP) lcnt[tid] = 0;
    __syncthreads();
    const int w = tid >> 6, lane = tid & 63;
#pragma unroll 1
    for (int t = 0; t < RBLK / 4; ++t) {
        const int lt = w * (RBLK / 4) + t;
        const int token = blockIdx.x * RBLK + lt;
        const float* xr = x3 + (size_t)token * DIM;
        float a[NEXP];
#pragma unroll
        for (int e = 0; e < NEXP; e++) a[e] = 0.f;
#pragma unroll
        for (int d0 = 0; d0 < DIM; d0 += 64) {
            float xv = xr[d0 + lane];
#pragma unroll
            for (int e = 0; e < NEXP; e++) a[e] += xv * wl[e][d0 + lane];
        }
#pragma unroll
        for (int e = 0; e < NEXP; e++)
#pragma unroll
            for (int off = 32; off; off >>= 1) a[e] += __shfl_xor(a[e], off);
        if (lane == 0) {
            int i1 = 0; float v1 = a[0];
#pragma unroll
            for (int e = 1; e < NEXP; e++) if (a[e] > v1) { v1 = a[e]; i1 = e; }
            int i2 = -1; float v2 = -3.4e38f;
#pragma unroll
            for (int e = 0; e < NEXP; e++) if (e != i1 && a[e] > v2) { v2 = a[e]; i2 = e; }
            float e2 = expf(v2 - v1);
            float g1 = 1.0f / (1.0f + e2);
            texp[lt * 2]      = i1; tgate[lt * 2]      = g1;
            texp[lt * 2 + 1]  = i2; tgate[lt * 2 + 1]  = 1.0f - g1;
        }
    }
    __syncthreads();
    if (tid < RBLK * 2) lslot[tid] = atomicAdd(&lcnt[texp[tid]], 1);
    __syncthreads();
    if (tid < NEXP) lbase[tid] = atomicAdd(&cnt[tid * 32], lcnt[tid]);
    __syncthreads();
    if (tid < RBLK * 2) {
        const int e = texp[tid];
        const int asg = blockIdx.x * (RBLK * 2) + tid;   // token*2 + k
        aid[e * NTOK + lbase[e] + lslot[tid]] = asg;
        gate[asg] = tgate[tid];
    }
}

// ======== expert GEMMs, 8-wave 256-row-tile counted-vmcnt structure ========
template <int EG, int KDIM, int AROWSHIFT>
__global__ __launch_bounds__(512, 2) void egemm8_kernel(
    const half_t* __restrict__ Ain,
    const half_t* __restrict__ W,
    const float* __restrict__ ebias,
    const int* __restrict__ cnt, const int* __restrict__ aid,
    const float* __restrict__ gate,
    half_t* __restrict__ Oh,
    float* __restrict__ Of,
    int Nc)
{
    const int ntPerE = Nc / 128;
    const int bid = blockIdx.x;
    const int e   = bid / (32 * ntPerE);
    const int rem = bid % (32 * ntPerE);
    const int mt  = rem / ntPerE, nt = rem % ntPerE;
    const int ne  = cnt[e * 32];
    if (mt * 256 >= ne) return;

    constexpr int TOT = 8192 + 4096;
    __shared__ __align__(16) half_t lds[2 * TOT];
    __shared__ int rowmap[256];
    const int tid = threadIdx.x;
    {
        int slot = mt * 256 + tid;
        if (tid < 256) rowmap[tid] = (slot < ne) ? aid[e * NTOK + slot] : -1;
    }
    __syncthreads();

    const int lane = tid & 63, wid = tid >> 6;
    const int wr = wid >> 1, wc = wid & 1;
    const int l31 = lane & 31, l5 = lane >> 5;

    const half_t* gsrc[3];
    const half_t* Wb = W + (size_t)e * Nc * KDIM;
#pragma unroll
    for (int i = 0; i < 3; i++) {
        int c = tid + 512 * i;
        if (c < 1024) {
            int r = c >> 2, ss = (c & 3) ^ ((r >> 1) & 3);
            int a = rowmap[r];
            gsrc[i] = Ain + (size_t)(a >= 0 ? (a >> AROWSHIFT) : 0) * KDIM + ss * 8;
        } else {
            int cb = c - 1024;
            int r = cb >> 2, ss = (cb & 3) ^ ((r >> 1) & 3);
            gsrc[i] = Wb + (size_t)(nt * 128 + r) * KDIM + ss * 8;
        }
    }

    int oa[2][2], ob[2][2];
#pragma unroll
    for (int m = 0; m < 2; m++)
#pragma unroll
        for (int kh = 0; kh < 2; kh++) {
            int ra = wr * 64 + m * 32 + l31;
            oa[m][kh] = ra * 32 + (((l5 + 2 * kh) ^ ((ra >> 1) & 3)) << 3);
        }
#pragma unroll
    for (int n = 0; n < 2; n++)
#pragma unroll
        for (int kh = 0; kh < 2; kh++) {
            int rb = wc * 64 + n * 32 + l31;
            ob[n][kh] = 8192 + rb * 32 + (((l5 + 2 * kh) ^ ((rb >> 1) & 3)) << 3);
        }

    f32x16 acc[2][2];
#pragma unroll
    for (int m = 0; m < 2; m++)
#pragma unroll
        for (int n = 0; n < 2; n++)
#pragma unroll
            for (int q = 0; q < 16; q++) acc[m][n][q] = 0.f;

    auto stage = [&](int bsel, int kof) {
#pragma unroll
        for (int i = 0; i < 3; i++)
            gl16(gsrc[i] + kof, &lds[bsel * TOT + (tid + 512 * i) * 8]);
    };
    auto compute = [&](int p) {
        const half_t* buf = &lds[p ? TOT : 0];
        __builtin_amdgcn_s_setprio(1);
#pragma unroll
        for (int kh = 0; kh < 2; kh++) {
            f16x8 a0 = *(const f16x8*)(buf + oa[0][kh]);
            f16x8 a1 = *(const f16x8*)(buf + oa[1][kh]);
            f16x8 b0 = *(const f16x8*)(buf + ob[0][kh]);
            f16x8 b1 = *(const f16x8*)(buf + ob[1][kh]);
            acc[0][0] = MFMA32(a0, b0, acc[0][0]);
            acc[0][1] = MFMA32(a0, b1, acc[0][1]);
            acc[1][0] = MFMA32(a1, b0, acc[1][0]);
            acc[1][1] = MFMA32(a1, b1, acc[1][1]);
        }
        __builtin_amdgcn_s_setprio(0);
    };

    const int nsteps = KDIM / 32;
    stage(0, 0);
#pragma unroll 1
    for (int s = 0; s < nsteps - 1; ++s) {
        stage((s + 1) & 1, (s + 1) * 32);
        asm volatile("s_waitcnt vmcnt(3)" ::: "memory");
        __builtin_amdgcn_s_barrier();
        compute(s & 1);
        __builtin_amdgcn_s_barrier();
    }
    asm volatile("s_waitcnt vmcnt(0)" ::: "memory");
    __builtin_amdgcn_s_barrier();
    compute((nsteps - 1) & 1);

    const int er = 4 * l5;
#pragma unroll
    for (int m = 0; m < 2; m++)
#pragma unroll
        for (int reg = 0; reg < 16; reg++) {
            int rloc = wr * 64 + m * 32 + er + 8 * (reg >> 2) + (reg & 3);
            int a = rowmap[rloc];
            if (a >= 0) {
#pragma unroll
                for (int n = 0; n < 2; n++) {
                    int cc = nt * 128 + wc * 64 + n * 32 + l31;
                    float v = acc[m][n][reg] + ebias[e * Nc + cc];
                    if (EG == 1) {
                        Oh[(size_t)a * Nc + cc] = (half_t)gelu_exact(v);
                    } else {
                        Of[(size_t)a * Nc + cc] = v * gate[a];
                    }
                }
            }
        }
}

// ---------------- combine two expert outputs per token + final LN ----------------
__global__ __launch_bounds__(256) void combine_lnf_kernel(
    const float* __restrict__ Ye, const float* __restrict__ g, const float* __restrict__ b,
    float* __restrict__ out)
{
    const int t = blockIdx.x, tid = threadIdx.x;
    __shared__ float red[4];
    float2 y0 = reinterpret_cast<const float2*>(Ye + (size_t)(2 * t) * DIM)[tid];
    float2 y1 = reinterpret_cast<const float2*>(Ye + (size_t)(2 * t + 1) * DIM)[tid];
    float z0 = y0.x + y1.x, z1 = y0.y + y1.y;
    float mean = block_sum4(z0 + z1, red, tid) * (1.0f / DIM);
    float d0 = z0 - mean, d1 = z1 - mean;
    float var = block_sum4(d0 * d0 + d1 * d1, red, tid) * (1.0f / DIM);
    float rstd = rsqrtf(var + 1e-5f);
    int d = tid * 2;
    out[(size_t)t * DIM + d]     = d0 * rstd * g[d]     + b[d];
    out[(size_t)t * DIM + d + 1] = d1 * rstd * g[d + 1] + b[d + 1];
    if (t == 0 && tid == 0) out[(size_t)NTOK * DIM] = 0.f;  // aux_loss
}

extern "C" void kernel_launch(void* const* d_in, const int* in_sizes, int n_in,
                              void* d_out, int out_size, void* d_ws, size_t ws_size,
                              hipStream_t stream)
{
    (void)in_sizes; (void)n_in; (void)out_size; (void)ws_size;
    const float* x    = (const float*)d_in[0];
    const float* ln1g = (const float*)d_in[1];
    const float* ln1b = (const float*)d_in[2];
    const float* w1   = (const float*)d_in[3];
    const float* b1   = (const float*)d_in[4];
    const float* w2   = (const float*)d_in[5];
    const float* b2   = (const float*)d_in[6];
    const float* ln2g = (const float*)d_in[7];
    const float* ln2b = (const float*)d_in[8];
    const float* wrm  = (const float*)d_in[9];
    const float* ew1  = (const float*)d_in[10];
    const float* eb1  = (const float*)d_in[11];
    const float* ew2  = (const float*)d_in[12];
    const float* eb2  = (const float*)d_in[13];
    const float* lnfg = (const float*)d_in[14];
    const float* lnfb = (const float*)d_in[15];
    float* out = (float*)d_out;

    char* w = (char*)d_ws;
    size_t off = 0;
    auto take = [&](size_t bytes) {
        char* p = w + off;
        off += bytes;
        off = (off + 255) & ~(size_t)255;
        return p;
    };
    half_t* xh_h  = (half_t*)take((size_t)NTOK * DIM * 2);   // also split-K partial p1 (f32, 16MB)
    half_t* xh_l  = (half_t*)take((size_t)NTOK * DIM * 2);
    half_t* w1t_h = (half_t*)take((size_t)DIM * MHID * 2);
    half_t* w1t_l = (half_t*)take((size_t)DIM * MHID * 2);
    half_t* w2t_h = (half_t*)take((size_t)MHID * DIM * 2);
    half_t* w2t_l = (half_t*)take((size_t)MHID * DIM * 2);
    char*   big   = take((size_t)NTOK * MHID * 2 * 2);        // 64 MiB: a1 hi/lo, later He + Ye
    half_t* a1h   = (half_t*)big;
    half_t* a1l   = (half_t*)(big + (size_t)NTOK * MHID * 2);
    half_t* heh   = (half_t*)big;                              // alias (a1 dead after gemm8<0>)
    float*  yef   = (float*)(big + (size_t)NTOK * MHID * 2);   // alias
    float*  x3f   = (float*)take((size_t)NTOK * DIM * 4);      // split-K partial p0, then x3 f32
    half_t* x3h   = (half_t*)take((size_t)NTOK * DIM * 2);
    half_t* ew1t  = (half_t*)take((size_t)NEXP * DIM * EHID * 2);
    half_t* ew2t  = (half_t*)take((size_t)NEXP * EHID * DIM * 2);
    int*    cnt   = (int*)take(1024);                          // 8 experts, 128 B apart
    int*    aid   = (int*)take((size_t)NEXP * NTOK * 4);
    float*  gate  = (float*)take((size_t)NTOK * 2 * 4);

    float* p0 = x3f;
    float* p1 = (float*)xh_h;   // xh_h+xh_l = contiguous 16 MB, dead after gemm8<1>

    ln1_split_kernel<<<NTOK, 256, 0, stream>>>(x, ln1g, ln1b, xh_h, xh_l, cnt);
    transpose_all_kernel<<<10240, dim3(32, 8), 0, stream>>>(
        w1, w2, ew1, ew2, w1t_h, w1t_l, w2t_h, w2t_l, ew1t, ew2t);
    // MLP GEMM1: [8192x512] @ [512x2048], gelu, split out.  256x256 tile, FINE phases.
    gemm8_kernel<1, 2, 1><<<dim3(NTOK / 256, MHID / 256, 1), 512, 0, stream>>>(
        xh_h, xh_l, w1t_h, w1t_l, b1, (float*)0, (float*)0, a1h, a1l, MHID, DIM, DIM);
    // MLP GEMM2: [8192x2048] @ [2048x512], 256x128 tile, split-K=2 raw partials (r9 structure)
    gemm8_kernel<0, 1, 0><<<dim3(NTOK / 256, DIM / 128, 2), 512, 0, stream>>>(
        a1h, a1l, w2t_h, w2t_l, (const float*)0, p0, p1, (half_t*)0, (half_t*)0, DIM, MHID, MHID / 2);
    resid_ln2_kernel<<<NTOK, 256, 0, stream>>>(x, p0, p1, b2, ln2g, ln2b, x3h);
    router_kernel<<<NTOK / RBLK, 256, 0, stream>>>(x3f, wrm, cnt, aid, gate);
    egemm8_kernel<1, DIM, 1><<<NEXP * 32 * (EHID / 128), 512, 0, stream>>>(
        x3h, ew1t, eb1, cnt, aid, (const float*)0, heh, (float*)0, EHID);
    egemm8_kernel<2, EHID, 0><<<NEXP * 32 * (DIM / 128), 512, 0, stream>>>(
        heh, ew2t, eb2, cnt, aid, gate, (half_t*)0, yef, DIM);
    combine_lnf_kernel<<<NTOK, 256, 0, stream>>>(yef, lnfg, lnfb, out);
}